// Round 2
// baseline (1766.739 us; speedup 1.0000x reference)
//
#include <hip/hip_runtime.h>
#include <math.h>

// ---------------------------------------------------------------------------
// SimpleVQAutoEncoder forward.
// Encoder (conv1+pool+gelu, conv2+pool) and VQ distances computed in FP64 to
// match the harness's numpy-fp64 reference argmin exactly (indices must match
// bit-for-bit; fp32 rounding flips near-tie argmins). Decoder fp32 (passed).
// Batch chunked 4x16 images to fit workspace.
// Outputs in d_out (float32): recon 4194304 | indices 262144 | loss 1
// ---------------------------------------------------------------------------

#define GELUF(v) (0.5f * (v) * (1.0f + erff((v) * 0.70710678118654752440f)))

// conv1 (1->16, 3x3 SAME) + maxpool2 + gelu, fp64. 16 images per chunk.
// threads = 16*128*128 = 262144.
__global__ __launch_bounds__(256) void k_conv1_f64(const float* __restrict__ x,
                                                   const float* __restrict__ w1,
                                                   const float* __restrict__ b1,
                                                   double* __restrict__ h1d,
                                                   int nbase) {
    int idx = blockIdx.x * 256 + threadIdx.x;
    int xo = idx & 127;
    int yo = (idx >> 7) & 127;
    int ln = idx >> 14;
    const float* xin = x + (size_t)(nbase + ln) * 65536;

    double patch[4][4];
    int y0 = 2 * yo - 1, x0 = 2 * xo - 1;
#pragma unroll
    for (int i = 0; i < 4; i++) {
        int iy = y0 + i;
        bool oy = (iy >= 0 && iy < 256);
#pragma unroll
        for (int j = 0; j < 4; j++) {
            int ix = x0 + j;
            patch[i][j] = (oy && ix >= 0 && ix < 256) ? (double)xin[iy * 256 + ix] : 0.0;
        }
    }

#pragma unroll
    for (int c = 0; c < 16; c++) {
        double m = -INFINITY;
#pragma unroll
        for (int sy = 0; sy < 2; sy++) {
#pragma unroll
            for (int sx = 0; sx < 2; sx++) {
                double acc = (double)b1[c];
#pragma unroll
                for (int ky = 0; ky < 3; ky++)
#pragma unroll
                    for (int kx = 0; kx < 3; kx++)
                        acc += (double)w1[c * 9 + ky * 3 + kx] * patch[sy + ky][sx + kx];
                m = fmax(m, acc);
            }
        }
        double g = 0.5 * m * (1.0 + erf(m * 0.70710678118654752440));
        h1d[((size_t)(ln * 16 + c) << 14) + (yo << 7) + xo] = g;
    }
}

// conv2 (16->32, 3x3 SAME) + maxpool2, fp64. Output channels processed in two
// halves of 16 to limit VGPR pressure. threads = 16*64*64 = 65536.
__global__ __launch_bounds__(256) void k_conv2_f64(const double* __restrict__ h1d,
                                                   const float* __restrict__ w2,
                                                   const float* __restrict__ b2,
                                                   double* __restrict__ h2d) {
    int idx = blockIdx.x * 256 + threadIdx.x;
    int xo = idx & 63;
    int yo = (idx >> 6) & 63;
    int ln = idx >> 12;
    const double* hb = h1d + (size_t)ln * 16 * 16384;

    for (int half = 0; half < 2; half++) {
        int c0 = half * 16;
        double mx[16];
#pragma unroll
        for (int c = 0; c < 16; c++) mx[c] = -INFINITY;

#pragma unroll
        for (int sy = 0; sy < 2; sy++) {
#pragma unroll
            for (int sx = 0; sx < 2; sx++) {
                int cy = 2 * yo + sy, cx = 2 * xo + sx;  // conv coords, 128-space
                double v[16];
#pragma unroll
                for (int c = 0; c < 16; c++) v[c] = (double)b2[c0 + c];
                for (int cin = 0; cin < 16; cin++) {
                    const double* ib = hb + (size_t)cin * 16384;
#pragma unroll
                    for (int ky = 0; ky < 3; ky++) {
                        int iy = cy + ky - 1;
                        bool oy = (iy >= 0 && iy < 128);
#pragma unroll
                        for (int kx = 0; kx < 3; kx++) {
                            int ix = cx + kx - 1;
                            double p = (oy && ix >= 0 && ix < 128) ? ib[iy * 128 + ix] : 0.0;
                            const float* wb = w2 + (c0 * 16 + cin) * 9 + ky * 3 + kx;
#pragma unroll
                            for (int c = 0; c < 16; c++)
                                v[c] += (double)wb[c * 144] * p;  // w2[((c'*16+cin)*3+ky)*3+kx]
                        }
                    }
                }
#pragma unroll
                for (int c = 0; c < 16; c++) mx[c] = fmax(mx[c], v[c]);
            }
        }
#pragma unroll
        for (int c = 0; c < 16; c++)
            h2d[((size_t)(ln * 32 + c0 + c) << 12) + (yo << 6) + xo] = mx[c];
    }
}

// VQ fp64: codebook cast to fp64 in LDS (128 KB), full fp64 distances,
// first-occurrence argmin. q gathered as fp32 (exact codebook values).
// threads = 16*4096 = 65536 per chunk.
__global__ __launch_bounds__(256) void k_vq_f64(const double* __restrict__ h2d,
                                                const float* __restrict__ cb,
                                                float* __restrict__ q,
                                                float* __restrict__ idx_out,
                                                float* __restrict__ loss_out,
                                                int nbase) {
    __shared__ double scbd[512 * 32];   // 128 KB
    __shared__ double sc2d[512];        // 4 KB
    __shared__ double wsumd[4];

    for (int i = threadIdx.x; i < 512 * 32; i += 256)
        scbd[i] = (double)cb[i];
    __syncthreads();
    for (int k = threadIdx.x; k < 512; k += 256) {
        double s = 0.0;
#pragma unroll
        for (int d = 0; d < 32; d++) s += scbd[k * 32 + d] * scbd[k * 32 + d];
        sc2d[k] = s;
    }
    __syncthreads();

    int pos = blockIdx.x * 256 + threadIdx.x;  // [0, 65536)
    int sp = pos & 4095;
    int ln = pos >> 12;
    const double* base = h2d + (size_t)ln * 32 * 4096 + sp;

    double xv[32];
    double x2 = 0.0;
#pragma unroll
    for (int d = 0; d < 32; d++) {
        xv[d] = base[(size_t)d * 4096];
        x2 += xv[d] * xv[d];
    }

    double best = INFINITY;
    int bi = 0;
    for (int k = 0; k < 512; k++) {
        double dot = 0.0;
#pragma unroll
        for (int d = 0; d < 32; d++) dot += xv[d] * scbd[k * 32 + d];
        double dist = x2 - 2.0 * dot + sc2d[k];
        if (dist < best) { best = dist; bi = k; }  // first-min tiebreak
    }

    double lsum = 0.0;
    float* qb = q + (size_t)(nbase + ln) * 32 * 4096 + sp;
#pragma unroll
    for (int d = 0; d < 32; d++) {
        double qd = scbd[bi * 32 + d];
        qb[(size_t)d * 4096] = (float)qd;  // exact: codebook values are fp32
        double diff = qd - xv[d];
        lsum += diff * diff;
    }
    idx_out[(size_t)(nbase + ln) * 4096 + sp] = (float)bi;

    // block reduction of commit-loss partial sums (fp64)
#pragma unroll
    for (int o = 32; o > 0; o >>= 1) lsum += __shfl_down(lsum, o);
    int lane = threadIdx.x & 63, w = threadIdx.x >> 6;
    if (lane == 0) wsumd[w] = lsum;
    __syncthreads();
    if (threadIdx.x == 0) {
        double s = wsumd[0] + wsumd[1] + wsumd[2] + wsumd[3];
        atomicAdd(loss_out, (float)(s * (1.0 / 8388608.0)));  // mean over 64*4096*32
    }
}

// upsample2 + conv3 (32->16, 3x3 SAME) + gelu, fp32. threads = 64*128*128.
__global__ __launch_bounds__(256) void k_conv3(const float* __restrict__ q,
                                               const float* __restrict__ w3,
                                               const float* __restrict__ b3,
                                               float* __restrict__ h3) {
    int idx = blockIdx.x * 256 + threadIdx.x;
    int xo = idx & 127;
    int yo = (idx >> 7) & 127;
    int n  = idx >> 14;
    const float* qb = q + (size_t)n * 32 * 4096;

    float acc[16];
#pragma unroll
    for (int c = 0; c < 16; c++) acc[c] = b3[c];

#pragma unroll
    for (int ky = 0; ky < 3; ky++) {
        int iy = yo + ky - 1;
        if (iy < 0 || iy >= 128) continue;
        int qy = iy >> 1;
#pragma unroll
        for (int kx = 0; kx < 3; kx++) {
            int ix = xo + kx - 1;
            if (ix < 0 || ix >= 128) continue;
            int qx = ix >> 1;
            const float* qp = qb + (qy << 6) + qx;
            for (int cin = 0; cin < 32; cin++) {
                float v = qp[(size_t)cin * 4096];
                const float* wb = w3 + cin * 9 + ky * 3 + kx;
#pragma unroll
                for (int c = 0; c < 16; c++)
                    acc[c] += wb[c * 288] * v;  // w3[((c*32+cin)*3+ky)*3+kx]
            }
        }
    }
#pragma unroll
    for (int c = 0; c < 16; c++)
        h3[((size_t)(n * 16 + c) << 14) + (yo << 7) + xo] = GELUF(acc[c]);
}

// upsample2 + conv4 (16->1, 3x3 SAME) + clip, fp32. threads = 64*256*256.
__global__ __launch_bounds__(256) void k_conv4(const float* __restrict__ h3,
                                               const float* __restrict__ w4,
                                               const float* __restrict__ b4,
                                               float* __restrict__ out) {
    int idx = blockIdx.x * 256 + threadIdx.x;
    int xo = idx & 255;
    int yo = (idx >> 8) & 255;
    int n  = idx >> 16;
    const float* hb = h3 + (size_t)n * 16 * 16384;

    float acc = b4[0];
#pragma unroll
    for (int ky = 0; ky < 3; ky++) {
        int iy = yo + ky - 1;
        if (iy < 0 || iy >= 256) continue;
        int hy = iy >> 1;
#pragma unroll
        for (int kx = 0; kx < 3; kx++) {
            int ix = xo + kx - 1;
            if (ix < 0 || ix >= 256) continue;
            int hx = ix >> 1;
            const float* hp = hb + (hy << 7) + hx;
#pragma unroll
            for (int cin = 0; cin < 16; cin++)
                acc += w4[cin * 9 + ky * 3 + kx] * hp[(size_t)cin * 16384];
        }
    }
    out[idx] = fminf(fmaxf(acc, -1.0f), 1.0f);
}

extern "C" void kernel_launch(void* const* d_in, const int* in_sizes, int n_in,
                              void* d_out, int out_size, void* d_ws, size_t ws_size,
                              hipStream_t stream) {
    const float* x  = (const float*)d_in[0];
    const float* w1 = (const float*)d_in[1];
    const float* b1 = (const float*)d_in[2];
    const float* w2 = (const float*)d_in[3];
    const float* b2 = (const float*)d_in[4];
    const float* cb = (const float*)d_in[5];
    const float* w3 = (const float*)d_in[6];
    const float* b3 = (const float*)d_in[7];
    const float* w4 = (const float*)d_in[8];
    const float* b4 = (const float*)d_in[9];

    float* out      = (float*)d_out;
    float* idx_out  = out + 4194304;
    float* loss_out = out + 4194304 + 262144;

    char* ws = (char*)d_ws;
    float*  qbuf = (float*)(ws);                       // [0,32M)  fp32 q, full batch
    double* h1d  = (double*)(ws + (size_t)33554432);   // [32M,64M) fp64, 16-img chunk
    double* h2d  = (double*)(ws + (size_t)67108864);   // [64M,80M) fp64, 16-img chunk
    float*  h3   = (float*)(ws + (size_t)33554432);    // [32M,96M) fp32 (after chunks)

    hipMemsetAsync(loss_out, 0, 4, stream);

    for (int c = 0; c < 4; c++) {
        int nbase = c * 16;
        k_conv1_f64<<<1024, 256, 0, stream>>>(x, w1, b1, h1d, nbase);
        k_conv2_f64<<<256, 256, 0, stream>>>(h1d, w2, b2, h2d);
        k_vq_f64<<<256, 256, 0, stream>>>(h2d, cb, qbuf, idx_out, loss_out, nbase);
    }
    k_conv3<<<4096, 256, 0, stream>>>(qbuf, w3, b3, h3);
    k_conv4<<<16384, 256, 0, stream>>>(h3, w4, b4, out);
}

// Round 3
// 1212.181 us; speedup vs baseline: 1.4575x; 1.4575x over previous
//
#include <hip/hip_runtime.h>
#include <math.h>

// ---------------------------------------------------------------------------
// SimpleVQAutoEncoder forward.
// fp32 encoder + VQ with near-tie flagging; fp64 repair pass recomputes the
// full encoder chain for flagged positions only (argmin must match numpy fp64
// exactly; recon depends only on codebook[idx], loss tolerance 2%).
// Decoder: upsample2+conv == 2x2 conv with parity-combined weights (prep
// kernel pre-sums taps); thread per 2x2 output block -> wave-uniform weight
// index (scalar loads) + float2 coalesced stores.
// Outputs d_out (fp32): recon 4194304 | indices 262144 | loss 1
// Workspace: h1/h3 [0,64M) | h2/q in-place [64M,96M) | wc3/wc4/nflag/flags tail
// ---------------------------------------------------------------------------

#define GELUF(v) (0.5f * (v) * (1.0f + erff((v) * 0.70710678118654752440f)))
#define MAXFLAG 65536

// conv1 (1->16) + maxpool2 + gelu, fp32. threads = 64*128*128.
__global__ __launch_bounds__(256) void k_conv1(const float* __restrict__ x,
                                               const float* __restrict__ w1,
                                               const float* __restrict__ b1,
                                               float* __restrict__ h1) {
    int idx = blockIdx.x * 256 + threadIdx.x;
    int xo = idx & 127;
    int yo = (idx >> 7) & 127;
    int n  = idx >> 14;
    const float* xin = x + (size_t)n * 65536;

    float patch[4][4];
    int y0 = 2 * yo - 1, x0 = 2 * xo - 1;
#pragma unroll
    for (int i = 0; i < 4; i++) {
        int iy = y0 + i;
        bool oy = (iy >= 0 && iy < 256);
#pragma unroll
        for (int j = 0; j < 4; j++) {
            int ix = x0 + j;
            patch[i][j] = (oy && ix >= 0 && ix < 256) ? xin[iy * 256 + ix] : 0.0f;
        }
    }
#pragma unroll
    for (int c = 0; c < 16; c++) {
        float m = -INFINITY;
#pragma unroll
        for (int sy = 0; sy < 2; sy++)
#pragma unroll
            for (int sx = 0; sx < 2; sx++) {
                float acc = b1[c];
#pragma unroll
                for (int ky = 0; ky < 3; ky++)
#pragma unroll
                    for (int kx = 0; kx < 3; kx++)
                        acc += w1[c * 9 + ky * 3 + kx] * patch[sy + ky][sx + kx];
                m = fmaxf(m, acc);
            }
        h1[((size_t)(n * 16 + c) << 14) + (yo << 7) + xo] = GELUF(m);
    }
}

// conv2 (16->32) + maxpool2, fp32. threads = 64*64*64.
__global__ __launch_bounds__(256) void k_conv2(const float* __restrict__ h1,
                                               const float* __restrict__ w2,
                                               const float* __restrict__ b2,
                                               float* __restrict__ h2) {
    int idx = blockIdx.x * 256 + threadIdx.x;
    int xo = idx & 63;
    int yo = (idx >> 6) & 63;
    int n  = idx >> 12;
    const float* hb = h1 + (size_t)n * 16 * 16384;

    float mx[32];
#pragma unroll
    for (int c = 0; c < 32; c++) mx[c] = -INFINITY;

#pragma unroll
    for (int sy = 0; sy < 2; sy++)
#pragma unroll
        for (int sx = 0; sx < 2; sx++) {
            int cy = 2 * yo + sy, cx = 2 * xo + sx;
            float v[32];
#pragma unroll
            for (int c = 0; c < 32; c++) v[c] = b2[c];
            for (int cin = 0; cin < 16; cin++) {
                const float* ib = hb + (size_t)cin * 16384;
#pragma unroll
                for (int ky = 0; ky < 3; ky++) {
                    int iy = cy + ky - 1;
                    bool oy = (iy >= 0 && iy < 128);
#pragma unroll
                    for (int kx = 0; kx < 3; kx++) {
                        int ix = cx + kx - 1;
                        float p = (oy && ix >= 0 && ix < 128) ? ib[iy * 128 + ix] : 0.0f;
                        const float* wb = w2 + cin * 9 + ky * 3 + kx;
#pragma unroll
                        for (int c = 0; c < 32; c++)
                            v[c] += wb[c * 144] * p;
                    }
                }
            }
#pragma unroll
            for (int c = 0; c < 32; c++) mx[c] = fmaxf(mx[c], v[c]);
        }
#pragma unroll
    for (int c = 0; c < 32; c++)
        h2[((size_t)(n * 32 + c) << 12) + (yo << 6) + xo] = mx[c];
}

// VQ fp32 with near-tie flagging. q written in-place over h2 (own elements
// read before written). threads = 262144.
__global__ __launch_bounds__(256) void k_vq32(const float* __restrict__ h2,
                                              const float* __restrict__ cb,
                                              float* __restrict__ q,
                                              float* __restrict__ idx_out,
                                              float* __restrict__ loss_out,
                                              int* __restrict__ nflag,
                                              int* __restrict__ flags) {
    __shared__ float scb[512 * 32];
    __shared__ float sc2[512];
    __shared__ float wsum[4];

    for (int i = threadIdx.x; i < 512 * 32 / 4; i += 256)
        ((float4*)scb)[i] = ((const float4*)cb)[i];
    __syncthreads();
    for (int k = threadIdx.x; k < 512; k += 256) {
        float s = 0.0f;
#pragma unroll
        for (int d = 0; d < 32; d++) s += scb[k * 32 + d] * scb[k * 32 + d];
        sc2[k] = s;
    }
    __syncthreads();

    int pos = blockIdx.x * 256 + threadIdx.x;
    int sp = pos & 4095;
    int n  = pos >> 12;
    const float* base = h2 + ((size_t)(n * 32) << 12) + sp;

    float xv[32];
    float x2 = 0.0f;
#pragma unroll
    for (int d = 0; d < 32; d++) {
        xv[d] = base[(size_t)d << 12];
        x2 += xv[d] * xv[d];
    }

    float best = INFINITY, best2 = INFINITY;
    int bi = 0;
    const float4* scb4 = (const float4*)scb;
    for (int k = 0; k < 512; k++) {
        float dot = 0.0f;
#pragma unroll
        for (int j = 0; j < 8; j++) {
            float4 c4 = scb4[k * 8 + j];
            dot += xv[j * 4 + 0] * c4.x + xv[j * 4 + 1] * c4.y +
                   xv[j * 4 + 2] * c4.z + xv[j * 4 + 3] * c4.w;
        }
        float dist = x2 - 2.0f * dot + sc2[k];
        if (dist < best) { best2 = best; best = dist; bi = k; }
        else if (dist < best2) best2 = dist;
    }

    float lsum = 0.0f;
    float* qb = q + ((size_t)(n * 32) << 12) + sp;
#pragma unroll
    for (int d = 0; d < 32; d++) {
        float qd = scb[bi * 32 + d];
        qb[(size_t)d << 12] = qd;
        float diff = qd - xv[d];
        lsum += diff * diff;
    }
    idx_out[pos] = (float)bi;

    // flag near-ties for fp64 repair
    float eps = 0.05f + 0.002f * fabsf(best);
    if (best2 - best < eps) {
        int slot = atomicAdd(nflag, 1);
        if (slot < MAXFLAG) flags[slot] = pos;
    }

#pragma unroll
    for (int o = 32; o > 0; o >>= 1) lsum += __shfl_down(lsum, o);
    int lane = threadIdx.x & 63, w = threadIdx.x >> 6;
    if (lane == 0) wsum[w] = lsum;
    __syncthreads();
    if (threadIdx.x == 0)
        atomicAdd(loss_out, (wsum[0] + wsum[1] + wsum[2] + wsum[3]) * (1.0f / 8388608.0f));
}

// fp64 repair: one wave per flagged position, recompute conv1->gelu->conv2->
// argmin exactly; rewrite idx and q. (Loss delta from flips < 1e-8, ignored.)
__global__ __launch_bounds__(64) void k_repair(const float* __restrict__ x,
                                               const float* __restrict__ w1,
                                               const float* __restrict__ b1,
                                               const float* __restrict__ w2,
                                               const float* __restrict__ b2,
                                               const float* __restrict__ cb,
                                               float* __restrict__ q,
                                               float* __restrict__ idx_out,
                                               const int* __restrict__ nflag,
                                               const int* __restrict__ flags) {
    __shared__ double h1w[16][16];  // [cin][pix(4x4)]
    __shared__ double xvd[32];
    int lane = threadIdx.x;
    int cnt = *nflag;
    if (cnt > MAXFLAG) cnt = MAXFLAG;

    for (int fi = blockIdx.x; fi < cnt; fi += gridDim.x) {
        int pos = flags[fi];
        int n = pos >> 12, sp = pos & 4095, yo = sp >> 6, xo = sp & 63;

        // Step A: 4x4 h1 window (16 ch) in fp64. lane -> (pix, channel group)
        int pix = lane >> 2, cg = lane & 3;
        int dy = pix >> 2, dx = pix & 3;
        int yh = 2 * yo - 1 + dy, xh = 2 * xo - 1 + dx;
        double hv[4] = {0.0, 0.0, 0.0, 0.0};
        if (yh >= 0 && yh < 128 && xh >= 0 && xh < 128) {
            const float* xin = x + (size_t)n * 65536;
            double patch[4][4];
            int y0 = 2 * yh - 1, x0 = 2 * xh - 1;
#pragma unroll
            for (int i = 0; i < 4; i++) {
                int iy = y0 + i;
                bool oy = (iy >= 0 && iy < 256);
#pragma unroll
                for (int j = 0; j < 4; j++) {
                    int ix = x0 + j;
                    patch[i][j] = (oy && ix >= 0 && ix < 256) ? (double)xin[iy * 256 + ix] : 0.0;
                }
            }
#pragma unroll
            for (int j = 0; j < 4; j++) {
                int c = cg * 4 + j;
                double m = -INFINITY;
#pragma unroll
                for (int sy = 0; sy < 2; sy++)
#pragma unroll
                    for (int sx = 0; sx < 2; sx++) {
                        double acc = (double)b1[c];
#pragma unroll
                        for (int ky = 0; ky < 3; ky++)
#pragma unroll
                            for (int kx = 0; kx < 3; kx++)
                                acc += (double)w1[c * 9 + ky * 3 + kx] * patch[sy + ky][sx + kx];
                        m = fmax(m, acc);
                    }
                hv[j] = 0.5 * m * (1.0 + erf(m * 0.70710678118654752440));
            }
        }
        __syncthreads();  // protect LDS reuse across fi iterations
#pragma unroll
        for (int j = 0; j < 4; j++) h1w[cg * 4 + j][pix] = hv[j];
        __syncthreads();

        // Step B: conv2+pool fp64, lane < 32 = cout
        if (lane < 32) {
            double bb = (double)b2[lane];
            double acc[2][2] = {{bb, bb}, {bb, bb}};
            for (int cin = 0; cin < 16; cin++)
#pragma unroll
                for (int ky = 0; ky < 3; ky++)
#pragma unroll
                    for (int kx = 0; kx < 3; kx++) {
                        double wv = (double)w2[((lane * 16 + cin) * 3 + ky) * 3 + kx];
#pragma unroll
                        for (int sy = 0; sy < 2; sy++)
#pragma unroll
                            for (int sx = 0; sx < 2; sx++)
                                acc[sy][sx] += wv * h1w[cin][(sy + ky) * 4 + (sx + kx)];
                    }
            xvd[lane] = fmax(fmax(acc[0][0], acc[0][1]), fmax(acc[1][0], acc[1][1]));
        }
        __syncthreads();

        // Step C: fp64 distances, 8 codes per lane, first-min argmin
        double x2 = 0.0;
        for (int d = 0; d < 32; d++) x2 += xvd[d] * xvd[d];
        double best = INFINITY;
        int bi = 0;
        for (int j = 0; j < 8; j++) {
            int k = lane * 8 + j;
            const float* cp = cb + k * 32;
            double c2 = 0.0, dot = 0.0;
#pragma unroll
            for (int d = 0; d < 32; d++) {
                double cd = (double)cp[d];
                c2 += cd * cd;
                dot += xvd[d] * cd;
            }
            double dist = x2 - 2.0 * dot + c2;
            if (dist < best) { best = dist; bi = k; }
        }
#pragma unroll
        for (int o = 32; o > 0; o >>= 1) {
            double od = __shfl_down(best, o);
            int oi = __shfl_down(bi, o);
            if (od < best || (od == best && oi < bi)) { best = od; bi = oi; }
        }
        bi = __shfl(bi, 0);

        if (lane == 0) idx_out[(size_t)n * 4096 + sp] = (float)bi;
        if (lane < 32) q[((size_t)(n * 32 + lane) << 12) + sp] = cb[bi * 32 + lane];
    }
}

// prep: parity-combined decoder weights.
// wc3[pp][cin(32)][tap(4)][cout(16)], wc4[pp][cin(16)][tap(4)]
__global__ __launch_bounds__(256) void k_prep(const float* __restrict__ w3,
                                              const float* __restrict__ w4,
                                              float* __restrict__ wc3,
                                              float* __restrict__ wc4) {
    const int masks[2][2] = {{1, 6}, {3, 4}};  // {ky0} {ky1,ky2} / {ky0,ky1} {ky2}
    for (int e = threadIdx.x; e < 8192; e += 256) {
        int cout = e & 15, tap = (e >> 4) & 3, cin = (e >> 6) & 31, pp = e >> 11;
        int rm = masks[pp >> 1][tap >> 1], cm = masks[pp & 1][tap & 1];
        float s = 0.0f;
        for (int ky = 0; ky < 3; ky++)
            if ((rm >> ky) & 1)
                for (int kx = 0; kx < 3; kx++)
                    if ((cm >> kx) & 1) s += w3[(cout * 32 + cin) * 9 + ky * 3 + kx];
        wc3[e] = s;
    }
    for (int e = threadIdx.x; e < 1024; e += 256) {
        int tap = e & 3, cin = (e >> 2) & 15, pp = e >> 6;
        int rm = masks[pp >> 1][tap >> 1], cm = masks[pp & 1][tap & 1];
        float s = 0.0f;
        for (int ky = 0; ky < 3; ky++)
            if ((rm >> ky) & 1)
                for (int kx = 0; kx < 3; kx++)
                    if ((cm >> kx) & 1) s += w4[cin * 9 + ky * 3 + kx];
        wc4[e] = s;
    }
}

// up2+conv3(32->16)+gelu via parity-collapsed 2x2 conv. Thread per 2x2 output
// block: wave-uniform weight index (scalar loads), float2 stores. thr=262144.
__global__ __launch_bounds__(256) void k_conv3n(const float* __restrict__ q,
                                                const float* __restrict__ wc3,
                                                const float* __restrict__ b3,
                                                float* __restrict__ h3) {
    int t = blockIdx.x * 256 + threadIdx.x;
    int b = t & 63, a = (t >> 6) & 63, n = t >> 12;

    float acc[2][2][16];
#pragma unroll
    for (int c = 0; c < 16; c++) {
        float bv = b3[c];
        acc[0][0][c] = bv; acc[0][1][c] = bv; acc[1][0][c] = bv; acc[1][1][c] = bv;
    }

    for (int cin = 0; cin < 32; cin++) {
        const float* qc = q + ((size_t)(n * 32 + cin) << 12);
        float v[3][3];
#pragma unroll
        for (int r = 0; r < 3; r++) {
            int qy = a - 1 + r;
            bool vy = (qy >= 0 && qy < 64);
#pragma unroll
            for (int cc = 0; cc < 3; cc++) {
                int qx = b - 1 + cc;
                v[r][cc] = (vy && qx >= 0 && qx < 64) ? qc[(qy << 6) + qx] : 0.0f;
            }
        }
        const float* wp = wc3 + cin * 64;
#pragma unroll
        for (int py = 0; py < 2; py++)
#pragma unroll
            for (int px = 0; px < 2; px++) {
                const float* wpp = wp + (py * 2 + px) * 2048;
#pragma unroll
                for (int dy = 0; dy < 2; dy++)
#pragma unroll
                    for (int dx = 0; dx < 2; dx++) {
                        float vv = v[py + dy][px + dx];
                        const float* wt = wpp + (dy * 2 + dx) * 16;
#pragma unroll
                        for (int c = 0; c < 16; c++)
                            acc[py][px][c] += wt[c] * vv;
                    }
            }
    }
#pragma unroll
    for (int c = 0; c < 16; c++)
#pragma unroll
        for (int py = 0; py < 2; py++) {
            float2 f2 = make_float2(GELUF(acc[py][0][c]), GELUF(acc[py][1][c]));
            *(float2*)(h3 + ((size_t)(n * 16 + c) << 14) + ((2 * a + py) << 7) + 2 * b) = f2;
        }
}

// up2+conv4(16->1)+clip, parity-collapsed. Thread per 2x2 block. thr=1048576.
__global__ __launch_bounds__(256) void k_conv4n(const float* __restrict__ h3,
                                                const float* __restrict__ wc4,
                                                const float* __restrict__ b4,
                                                float* __restrict__ out) {
    int t = blockIdx.x * 256 + threadIdx.x;
    int b = t & 127, a = (t >> 7) & 127, n = t >> 14;

    float bv = b4[0];
    float acc[2][2] = {{bv, bv}, {bv, bv}};

    for (int cin = 0; cin < 16; cin++) {
        const float* hc = h3 + ((size_t)(n * 16 + cin) << 14);
        float v[3][3];
#pragma unroll
        for (int r = 0; r < 3; r++) {
            int hy = a - 1 + r;
            bool vy = (hy >= 0 && hy < 128);
#pragma unroll
            for (int cc = 0; cc < 3; cc++) {
                int hx = b - 1 + cc;
                v[r][cc] = (vy && hx >= 0 && hx < 128) ? hc[(hy << 7) + hx] : 0.0f;
            }
        }
#pragma unroll
        for (int py = 0; py < 2; py++)
#pragma unroll
            for (int px = 0; px < 2; px++)
#pragma unroll
                for (int dy = 0; dy < 2; dy++)
#pragma unroll
                    for (int dx = 0; dx < 2; dx++)
                        acc[py][px] += wc4[(py * 2 + px) * 64 + cin * 4 + dy * 2 + dx] *
                                       v[py + dy][px + dx];
    }
#pragma unroll
    for (int py = 0; py < 2; py++) {
        float2 f2 = make_float2(fminf(fmaxf(acc[py][0], -1.0f), 1.0f),
                                fminf(fmaxf(acc[py][1], -1.0f), 1.0f));
        *(float2*)(out + (size_t)n * 65536 + (2 * a + py) * 256 + 2 * b) = f2;
    }
}

extern "C" void kernel_launch(void* const* d_in, const int* in_sizes, int n_in,
                              void* d_out, int out_size, void* d_ws, size_t ws_size,
                              hipStream_t stream) {
    const float* x  = (const float*)d_in[0];
    const float* w1 = (const float*)d_in[1];
    const float* b1 = (const float*)d_in[2];
    const float* w2 = (const float*)d_in[3];
    const float* b2 = (const float*)d_in[4];
    const float* cb = (const float*)d_in[5];
    const float* w3 = (const float*)d_in[6];
    const float* b3 = (const float*)d_in[7];
    const float* w4 = (const float*)d_in[8];
    const float* b4 = (const float*)d_in[9];

    float* out      = (float*)d_out;
    float* idx_out  = out + 4194304;
    float* loss_out = out + 4194304 + 262144;

    char* ws = (char*)d_ws;
    float* h1  = (float*)ws;                           // [0,64M) -> later h3
    float* h2  = (float*)(ws + (size_t)67108864);      // [64M,96M), q in-place
    float* h3  = (float*)ws;
    float* wc3 = (float*)(ws + (size_t)100663296);     // 32 KB
    float* wc4 = wc3 + 8192;                           // 4 KB
    int*   nflag = (int*)(ws + (size_t)100663296 + 36864);
    int*   flags = nflag + 16;                         // 256 KB

    hipMemsetAsync(loss_out, 0, 4, stream);
    hipMemsetAsync(nflag, 0, 4, stream);

    k_prep<<<1, 256, 0, stream>>>(w3, w4, wc3, wc4);
    k_conv1<<<4096, 256, 0, stream>>>(x, w1, b1, h1);
    k_conv2<<<1024, 256, 0, stream>>>(h1, w2, b2, h2);
    k_vq32<<<1024, 256, 0, stream>>>(h2, cb, h2, idx_out, loss_out, nflag, flags);
    k_repair<<<4096, 64, 0, stream>>>(x, w1, b1, w2, b2, cb, h2, idx_out, nflag, flags);
    k_conv3n<<<1024, 256, 0, stream>>>(h2, wc3, b3, h3);
    k_conv4n<<<4096, 256, 0, stream>>>(h3, wc4, b4, out);
}

// Round 4
// 963.221 us; speedup vs baseline: 1.8342x; 1.2585x over previous
//
#include <hip/hip_runtime.h>
#include <math.h>

// ---------------------------------------------------------------------------
// SimpleVQAutoEncoder forward.
// fp32 encoder + VQ with near-tie flagging; fp64 repair pass recomputes the
// full encoder chain for flagged positions only (argmin matches numpy fp64).
// conv2: LDS-tiled, one thread per conv position, in-wave shuffle maxpool.
// VQ: 2 positions/thread (amortize codebook LDS reads).
// Decoder: parity-collapsed 2x2 convs (upsample folded into weights).
// Outputs d_out (fp32): recon 4194304 | indices 262144 | loss 1
// ---------------------------------------------------------------------------

#define GELUF(v) (0.5f * (v) * (1.0f + erff((v) * 0.70710678118654752440f)))
#define MAXFLAG 65536

// conv1 (1->16) + maxpool2 + gelu, fp32. threads = 64*128*128.
__global__ __launch_bounds__(256) void k_conv1(const float* __restrict__ x,
                                               const float* __restrict__ w1,
                                               const float* __restrict__ b1,
                                               float* __restrict__ h1) {
    int idx = blockIdx.x * 256 + threadIdx.x;
    int xo = idx & 127;
    int yo = (idx >> 7) & 127;
    int n  = idx >> 14;
    const float* xin = x + (size_t)n * 65536;

    float patch[4][4];
    int y0 = 2 * yo - 1, x0 = 2 * xo - 1;
#pragma unroll
    for (int i = 0; i < 4; i++) {
        int iy = y0 + i;
        bool oy = (iy >= 0 && iy < 256);
#pragma unroll
        for (int j = 0; j < 4; j++) {
            int ix = x0 + j;
            patch[i][j] = (oy && ix >= 0 && ix < 256) ? xin[iy * 256 + ix] : 0.0f;
        }
    }
#pragma unroll
    for (int c = 0; c < 16; c++) {
        float m = -INFINITY;
#pragma unroll
        for (int sy = 0; sy < 2; sy++)
#pragma unroll
            for (int sx = 0; sx < 2; sx++) {
                float acc = b1[c];
#pragma unroll
                for (int ky = 0; ky < 3; ky++)
#pragma unroll
                    for (int kx = 0; kx < 3; kx++)
                        acc += w1[c * 9 + ky * 3 + kx] * patch[sy + ky][sx + kx];
                m = fmaxf(m, acc);
            }
        h1[((size_t)(n * 16 + c) << 14) + (yo << 7) + xo] = GELUF(m);
    }
}

// conv2 (16->32) + maxpool2, LDS-tiled. Block = 16x16 conv positions of one
// image; LDS = 16ch x 18x18 window. Thread = one conv position, all 32 couts;
// pool via shfl_xor(1) [x-pair] + shfl_xor(16) [y-pair]. grid = 64*64 blocks.
__global__ __launch_bounds__(256) void k_conv2t(const float* __restrict__ h1,
                                                const float* __restrict__ w2,
                                                const float* __restrict__ b2,
                                                float* __restrict__ h2) {
    __shared__ float s_in[16 * 324];  // [cin][18*18], 20.7 KB

    int tid = threadIdx.x;
    int n  = blockIdx.x >> 6;
    int tile = blockIdx.x & 63;
    int cx0 = (tile & 7) << 4;   // conv-space tile origin (128-grid)
    int cy0 = (tile >> 3) << 4;

    const float* hb = h1 + ((size_t)(n * 16) << 14);
    for (int e = tid; e < 5184; e += 256) {
        int cin = e / 324;
        int rem = e - cin * 324;
        int r = rem / 18;
        int c = rem - r * 18;
        int iy = cy0 - 1 + r, ix = cx0 - 1 + c;
        float v = 0.0f;
        if (iy >= 0 && iy < 128 && ix >= 0 && ix < 128)
            v = hb[((size_t)cin << 14) + iy * 128 + ix];
        s_in[e] = v;
    }
    __syncthreads();

    int lx  = tid & 15;    // conv x within tile
    int lyq = tid >> 4;    // conv y within tile

    float v[32];
#pragma unroll
    for (int c = 0; c < 32; c++) v[c] = b2[c];

    for (int cin = 0; cin < 16; cin++) {
        float p[9];
        const float* sp = s_in + cin * 324 + lyq * 18 + lx;
#pragma unroll
        for (int ky = 0; ky < 3; ky++)
#pragma unroll
            for (int kx = 0; kx < 3; kx++)
                p[ky * 3 + kx] = sp[ky * 18 + kx];
        const float* wb = w2 + cin * 9;  // + c*144 + t
#pragma unroll
        for (int c = 0; c < 32; c++) {
            float a = v[c];
#pragma unroll
            for (int t = 0; t < 9; t++) a += wb[c * 144 + t] * p[t];
            v[c] = a;
        }
    }

    // in-wave 2x2 maxpool: x-pair lane^1, y-pair lane^16
    bool active = ((lx & 1) == 0) && ((lyq & 1) == 0);
    int px = (cx0 >> 1) + (lx >> 1);
    int py = (cy0 >> 1) + (lyq >> 1);
    float* ob = h2 + ((size_t)(n * 32) << 12) + (py << 6) + px;
#pragma unroll
    for (int c = 0; c < 32; c++) {
        float m = v[c];
        m = fmaxf(m, __shfl_xor(m, 1));
        m = fmaxf(m, __shfl_xor(m, 16));
        if (active) ob[(size_t)c << 12] = m;
    }
}

// VQ fp32, 2 positions/thread, near-tie flagging. q in-place over h2.
// grid = 512 blocks * 256 threads * 2 pos = 262144.
__global__ __launch_bounds__(256) void k_vq32(const float* __restrict__ h2,
                                              const float* __restrict__ cb,
                                              float* __restrict__ q,
                                              float* __restrict__ idx_out,
                                              float* __restrict__ loss_out,
                                              int* __restrict__ nflag,
                                              int* __restrict__ flags) {
    __shared__ float scb[512 * 32];
    __shared__ float sc2[512];
    __shared__ float wsum[4];

    for (int i = threadIdx.x; i < 512 * 32 / 4; i += 256)
        ((float4*)scb)[i] = ((const float4*)cb)[i];
    __syncthreads();
    for (int k = threadIdx.x; k < 512; k += 256) {
        float s = 0.0f;
#pragma unroll
        for (int d = 0; d < 32; d++) s += scb[k * 32 + d] * scb[k * 32 + d];
        sc2[k] = s;
    }
    __syncthreads();

    int pos0 = (blockIdx.x * 256 + threadIdx.x) * 2;  // 2 consecutive positions
    int sp = pos0 & 4095;
    int n  = pos0 >> 12;
    const float* base = h2 + ((size_t)(n * 32) << 12) + sp;

    float xv[2][32];
    float x2[2] = {0.0f, 0.0f};
#pragma unroll
    for (int d = 0; d < 32; d++) {
#pragma unroll
        for (int p = 0; p < 2; p++) {
            float t = base[((size_t)d << 12) + p];
            xv[p][d] = t;
            x2[p] += t * t;
        }
    }

    float best[2] = {INFINITY, INFINITY}, best2[2] = {INFINITY, INFINITY};
    int bi[2] = {0, 0};
    const float4* scb4 = (const float4*)scb;
    for (int k = 0; k < 512; k++) {
        float dot0 = 0.0f, dot1 = 0.0f;
#pragma unroll
        for (int j = 0; j < 8; j++) {
            float4 c4 = scb4[k * 8 + j];
            dot0 += xv[0][j * 4 + 0] * c4.x + xv[0][j * 4 + 1] * c4.y +
                    xv[0][j * 4 + 2] * c4.z + xv[0][j * 4 + 3] * c4.w;
            dot1 += xv[1][j * 4 + 0] * c4.x + xv[1][j * 4 + 1] * c4.y +
                    xv[1][j * 4 + 2] * c4.z + xv[1][j * 4 + 3] * c4.w;
        }
        float d0 = x2[0] - 2.0f * dot0 + sc2[k];
        float d1 = x2[1] - 2.0f * dot1 + sc2[k];
        if (d0 < best[0]) { best2[0] = best[0]; best[0] = d0; bi[0] = k; }
        else if (d0 < best2[0]) best2[0] = d0;
        if (d1 < best[1]) { best2[1] = best[1]; best[1] = d1; bi[1] = k; }
        else if (d1 < best2[1]) best2[1] = d1;
    }

    float lsum = 0.0f;
    float* qb = q + ((size_t)(n * 32) << 12) + sp;
#pragma unroll
    for (int d = 0; d < 32; d++) {
#pragma unroll
        for (int p = 0; p < 2; p++) {
            float qd = scb[bi[p] * 32 + d];
            qb[((size_t)d << 12) + p] = qd;
            float diff = qd - xv[p][d];
            lsum += diff * diff;
        }
    }
#pragma unroll
    for (int p = 0; p < 2; p++) {
        idx_out[pos0 + p] = (float)bi[p];
        float eps = 0.05f + 0.002f * fabsf(best[p]);
        if (best2[p] - best[p] < eps) {
            int slot = atomicAdd(nflag, 1);
            if (slot < MAXFLAG) flags[slot] = pos0 + p;
        }
    }

#pragma unroll
    for (int o = 32; o > 0; o >>= 1) lsum += __shfl_down(lsum, o);
    int lane = threadIdx.x & 63, w = threadIdx.x >> 6;
    if (lane == 0) wsum[w] = lsum;
    __syncthreads();
    if (threadIdx.x == 0)
        atomicAdd(loss_out, (wsum[0] + wsum[1] + wsum[2] + wsum[3]) * (1.0f / 8388608.0f));
}

// fp64 repair: one wave per flagged position (unchanged from R3).
__global__ __launch_bounds__(64) void k_repair(const float* __restrict__ x,
                                               const float* __restrict__ w1,
                                               const float* __restrict__ b1,
                                               const float* __restrict__ w2,
                                               const float* __restrict__ b2,
                                               const float* __restrict__ cb,
                                               float* __restrict__ q,
                                               float* __restrict__ idx_out,
                                               const int* __restrict__ nflag,
                                               const int* __restrict__ flags) {
    __shared__ double h1w[16][16];
    __shared__ double xvd[32];
    int lane = threadIdx.x;
    int cnt = *nflag;
    if (cnt > MAXFLAG) cnt = MAXFLAG;

    for (int fi = blockIdx.x; fi < cnt; fi += gridDim.x) {
        int pos = flags[fi];
        int n = pos >> 12, sp = pos & 4095, yo = sp >> 6, xo = sp & 63;

        int pix = lane >> 2, cg = lane & 3;
        int dy = pix >> 2, dx = pix & 3;
        int yh = 2 * yo - 1 + dy, xh = 2 * xo - 1 + dx;
        double hv[4] = {0.0, 0.0, 0.0, 0.0};
        if (yh >= 0 && yh < 128 && xh >= 0 && xh < 128) {
            const float* xin = x + (size_t)n * 65536;
            double patch[4][4];
            int y0 = 2 * yh - 1, x0 = 2 * xh - 1;
#pragma unroll
            for (int i = 0; i < 4; i++) {
                int iy = y0 + i;
                bool oy = (iy >= 0 && iy < 256);
#pragma unroll
                for (int j = 0; j < 4; j++) {
                    int ix = x0 + j;
                    patch[i][j] = (oy && ix >= 0 && ix < 256) ? (double)xin[iy * 256 + ix] : 0.0;
                }
            }
#pragma unroll
            for (int j = 0; j < 4; j++) {
                int c = cg * 4 + j;
                double m = -INFINITY;
#pragma unroll
                for (int sy = 0; sy < 2; sy++)
#pragma unroll
                    for (int sx = 0; sx < 2; sx++) {
                        double acc = (double)b1[c];
#pragma unroll
                        for (int ky = 0; ky < 3; ky++)
#pragma unroll
                            for (int kx = 0; kx < 3; kx++)
                                acc += (double)w1[c * 9 + ky * 3 + kx] * patch[sy + ky][sx + kx];
                        m = fmax(m, acc);
                    }
                hv[j] = 0.5 * m * (1.0 + erf(m * 0.70710678118654752440));
            }
        }
        __syncthreads();
#pragma unroll
        for (int j = 0; j < 4; j++) h1w[cg * 4 + j][pix] = hv[j];
        __syncthreads();

        if (lane < 32) {
            double bb = (double)b2[lane];
            double acc[2][2] = {{bb, bb}, {bb, bb}};
            for (int cin = 0; cin < 16; cin++)
#pragma unroll
                for (int ky = 0; ky < 3; ky++)
#pragma unroll
                    for (int kx = 0; kx < 3; kx++) {
                        double wv = (double)w2[((lane * 16 + cin) * 3 + ky) * 3 + kx];
#pragma unroll
                        for (int sy = 0; sy < 2; sy++)
#pragma unroll
                            for (int sx = 0; sx < 2; sx++)
                                acc[sy][sx] += wv * h1w[cin][(sy + ky) * 4 + (sx + kx)];
                    }
            xvd[lane] = fmax(fmax(acc[0][0], acc[0][1]), fmax(acc[1][0], acc[1][1]));
        }
        __syncthreads();

        double x2 = 0.0;
        for (int d = 0; d < 32; d++) x2 += xvd[d] * xvd[d];
        double best = INFINITY;
        int bi = 0;
        for (int j = 0; j < 8; j++) {
            int k = lane * 8 + j;
            const float* cp = cb + k * 32;
            double c2 = 0.0, dot = 0.0;
#pragma unroll
            for (int d = 0; d < 32; d++) {
                double cd = (double)cp[d];
                c2 += cd * cd;
                dot += xvd[d] * cd;
            }
            double dist = x2 - 2.0 * dot + c2;
            if (dist < best) { best = dist; bi = k; }
        }
#pragma unroll
        for (int o = 32; o > 0; o >>= 1) {
            double od = __shfl_down(best, o);
            int oi = __shfl_down(bi, o);
            if (od < best || (od == best && oi < bi)) { best = od; bi = oi; }
        }
        bi = __shfl(bi, 0);

        if (lane == 0) idx_out[(size_t)n * 4096 + sp] = (float)bi;
        if (lane < 32) q[((size_t)(n * 32 + lane) << 12) + sp] = cb[bi * 32 + lane];
    }
}

// prep: parity-combined decoder weights (unchanged).
__global__ __launch_bounds__(256) void k_prep(const float* __restrict__ w3,
                                              const float* __restrict__ w4,
                                              float* __restrict__ wc3,
                                              float* __restrict__ wc4) {
    const int masks[2][2] = {{1, 6}, {3, 4}};
    for (int e = threadIdx.x; e < 8192; e += 256) {
        int cout = e & 15, tap = (e >> 4) & 3, cin = (e >> 6) & 31, pp = e >> 11;
        int rm = masks[pp >> 1][tap >> 1], cm = masks[pp & 1][tap & 1];
        float s = 0.0f;
        for (int ky = 0; ky < 3; ky++)
            if ((rm >> ky) & 1)
                for (int kx = 0; kx < 3; kx++)
                    if ((cm >> kx) & 1) s += w3[(cout * 32 + cin) * 9 + ky * 3 + kx];
        wc3[e] = s;
    }
    for (int e = threadIdx.x; e < 1024; e += 256) {
        int tap = e & 3, cin = (e >> 2) & 15, pp = e >> 6;
        int rm = masks[pp >> 1][tap >> 1], cm = masks[pp & 1][tap & 1];
        float s = 0.0f;
        for (int ky = 0; ky < 3; ky++)
            if ((rm >> ky) & 1)
                for (int kx = 0; kx < 3; kx++)
                    if ((cm >> kx) & 1) s += w4[cin * 9 + ky * 3 + kx];
        wc4[e] = s;
    }
}

// up2+conv3(32->16)+gelu, parity-collapsed (unchanged).
__global__ __launch_bounds__(256) void k_conv3n(const float* __restrict__ q,
                                                const float* __restrict__ wc3,
                                                const float* __restrict__ b3,
                                                float* __restrict__ h3) {
    int t = blockIdx.x * 256 + threadIdx.x;
    int b = t & 63, a = (t >> 6) & 63, n = t >> 12;

    float acc[2][2][16];
#pragma unroll
    for (int c = 0; c < 16; c++) {
        float bv = b3[c];
        acc[0][0][c] = bv; acc[0][1][c] = bv; acc[1][0][c] = bv; acc[1][1][c] = bv;
    }

    for (int cin = 0; cin < 32; cin++) {
        const float* qc = q + ((size_t)(n * 32 + cin) << 12);
        float v[3][3];
#pragma unroll
        for (int r = 0; r < 3; r++) {
            int qy = a - 1 + r;
            bool vy = (qy >= 0 && qy < 64);
#pragma unroll
            for (int cc = 0; cc < 3; cc++) {
                int qx = b - 1 + cc;
                v[r][cc] = (vy && qx >= 0 && qx < 64) ? qc[(qy << 6) + qx] : 0.0f;
            }
        }
        const float* wp = wc3 + cin * 64;
#pragma unroll
        for (int py = 0; py < 2; py++)
#pragma unroll
            for (int px = 0; px < 2; px++) {
                const float* wpp = wp + (py * 2 + px) * 2048;
#pragma unroll
                for (int dy = 0; dy < 2; dy++)
#pragma unroll
                    for (int dx = 0; dx < 2; dx++) {
                        float vv = v[py + dy][px + dx];
                        const float* wt = wpp + (dy * 2 + dx) * 16;
#pragma unroll
                        for (int c = 0; c < 16; c++)
                            acc[py][px][c] += wt[c] * vv;
                    }
            }
    }
#pragma unroll
    for (int c = 0; c < 16; c++)
#pragma unroll
        for (int py = 0; py < 2; py++) {
            float2 f2 = make_float2(GELUF(acc[py][0][c]), GELUF(acc[py][1][c]));
            *(float2*)(h3 + ((size_t)(n * 16 + c) << 14) + ((2 * a + py) << 7) + 2 * b) = f2;
        }
}

// up2+conv4(16->1)+clip, parity-collapsed (unchanged).
__global__ __launch_bounds__(256) void k_conv4n(const float* __restrict__ h3,
                                                const float* __restrict__ wc4,
                                                const float* __restrict__ b4,
                                                float* __restrict__ out) {
    int t = blockIdx.x * 256 + threadIdx.x;
    int b = t & 127, a = (t >> 7) & 127, n = t >> 14;

    float bv = b4[0];
    float acc[2][2] = {{bv, bv}, {bv, bv}};

    for (int cin = 0; cin < 16; cin++) {
        const float* hc = h3 + ((size_t)(n * 16 + cin) << 14);
        float v[3][3];
#pragma unroll
        for (int r = 0; r < 3; r++) {
            int hy = a - 1 + r;
            bool vy = (hy >= 0 && hy < 128);
#pragma unroll
            for (int cc = 0; cc < 3; cc++) {
                int hx = b - 1 + cc;
                v[r][cc] = (vy && hx >= 0 && hx < 128) ? hc[(hy << 7) + hx] : 0.0f;
            }
        }
#pragma unroll
        for (int py = 0; py < 2; py++)
#pragma unroll
            for (int px = 0; px < 2; px++)
#pragma unroll
                for (int dy = 0; dy < 2; dy++)
#pragma unroll
                    for (int dx = 0; dx < 2; dx++)
                        acc[py][px] += wc4[(py * 2 + px) * 64 + cin * 4 + dy * 2 + dx] *
                                       v[py + dy][px + dx];
    }
#pragma unroll
    for (int py = 0; py < 2; py++) {
        float2 f2 = make_float2(fminf(fmaxf(acc[py][0], -1.0f), 1.0f),
                                fminf(fmaxf(acc[py][1], -1.0f), 1.0f));
        *(float2*)(out + (size_t)n * 65536 + (2 * a + py) * 256 + 2 * b) = f2;
    }
}

extern "C" void kernel_launch(void* const* d_in, const int* in_sizes, int n_in,
                              void* d_out, int out_size, void* d_ws, size_t ws_size,
                              hipStream_t stream) {
    const float* x  = (const float*)d_in[0];
    const float* w1 = (const float*)d_in[1];
    const float* b1 = (const float*)d_in[2];
    const float* w2 = (const float*)d_in[3];
    const float* b2 = (const float*)d_in[4];
    const float* cb = (const float*)d_in[5];
    const float* w3 = (const float*)d_in[6];
    const float* b3 = (const float*)d_in[7];
    const float* w4 = (const float*)d_in[8];
    const float* b4 = (const float*)d_in[9];

    float* out      = (float*)d_out;
    float* idx_out  = out + 4194304;
    float* loss_out = out + 4194304 + 262144;

    char* ws = (char*)d_ws;
    float* h1  = (float*)ws;                           // [0,64M) -> later h3
    float* h2  = (float*)(ws + (size_t)67108864);      // [64M,96M), q in-place
    float* h3  = (float*)ws;
    float* wc3 = (float*)(ws + (size_t)100663296);     // 32 KB
    float* wc4 = wc3 + 8192;                           // 4 KB
    int*   nflag = (int*)(ws + (size_t)100663296 + 36864);
    int*   flags = nflag + 16;                         // 256 KB

    hipMemsetAsync(loss_out, 0, 4, stream);
    hipMemsetAsync(nflag, 0, 4, stream);

    k_prep<<<1, 256, 0, stream>>>(w3, w4, wc3, wc4);
    k_conv1<<<4096, 256, 0, stream>>>(x, w1, b1, h1);
    k_conv2t<<<4096, 256, 0, stream>>>(h1, w2, b2, h2);
    k_vq32<<<512, 256, 0, stream>>>(h2, cb, h2, idx_out, loss_out, nflag, flags);
    k_repair<<<4096, 64, 0, stream>>>(x, w1, b1, w2, b2, cb, h2, idx_out, nflag, flags);
    k_conv3n<<<1024, 256, 0, stream>>>(h2, wc3, b3, h3);
    k_conv4n<<<4096, 256, 0, stream>>>(h3, wc4, b4, out);
}

// Round 6
// 789.887 us; speedup vs baseline: 2.2367x; 1.2194x over previous
//
#include <hip/hip_runtime.h>
#include <math.h>

// ---------------------------------------------------------------------------
// SimpleVQAutoEncoder forward.
// fp32 encoder; VQ dots via split-bf16 MFMA (hi/lo decomposition, 3 chained
// mfma_f32_16x16x32_bf16 => fp32-accurate distances, err ~6e-4 << eps 0.05);
// near-tie flagging + fp64 repair pass keeps indices exactly == numpy fp64.
// Decoder: parity-collapsed 2x2 convs (upsample folded into weights).
// Outputs d_out (fp32): recon 4194304 | indices 262144 | loss 1
// ---------------------------------------------------------------------------

#define GELUF(v) (0.5f * (v) * (1.0f + erff((v) * 0.70710678118654752440f)))
#define MAXFLAG 65536

typedef __attribute__((ext_vector_type(8))) short short8;
typedef __attribute__((ext_vector_type(4))) short short4v;
typedef __attribute__((ext_vector_type(4))) float float4v;

static __device__ inline unsigned short f2bf(float f) {
    unsigned u = __float_as_uint(f);
    unsigned r = (u + 0x7FFFu + ((u >> 16) & 1u)) >> 16;
    return (unsigned short)r;
}
static __device__ inline float bf2f(unsigned short h) {
    return __uint_as_float(((unsigned)h) << 16);
}

// conv1 (1->16) + maxpool2 + gelu, fp32. threads = 64*128*128.
__global__ __launch_bounds__(256) void k_conv1(const float* __restrict__ x,
                                               const float* __restrict__ w1,
                                               const float* __restrict__ b1,
                                               float* __restrict__ h1) {
    int idx = blockIdx.x * 256 + threadIdx.x;
    int xo = idx & 127;
    int yo = (idx >> 7) & 127;
    int n  = idx >> 14;
    const float* xin = x + (size_t)n * 65536;

    float patch[4][4];
    int y0 = 2 * yo - 1, x0 = 2 * xo - 1;
#pragma unroll
    for (int i = 0; i < 4; i++) {
        int iy = y0 + i;
        bool oy = (iy >= 0 && iy < 256);
#pragma unroll
        for (int j = 0; j < 4; j++) {
            int ix = x0 + j;
            patch[i][j] = (oy && ix >= 0 && ix < 256) ? xin[iy * 256 + ix] : 0.0f;
        }
    }
#pragma unroll
    for (int c = 0; c < 16; c++) {
        float m = -INFINITY;
#pragma unroll
        for (int sy = 0; sy < 2; sy++)
#pragma unroll
            for (int sx = 0; sx < 2; sx++) {
                float acc = b1[c];
#pragma unroll
                for (int ky = 0; ky < 3; ky++)
#pragma unroll
                    for (int kx = 0; kx < 3; kx++)
                        acc += w1[c * 9 + ky * 3 + kx] * patch[sy + ky][sx + kx];
                m = fmaxf(m, acc);
            }
        h1[((size_t)(n * 16 + c) << 14) + (yo << 7) + xo] = GELUF(m);
    }
}

// conv2 (16->32) + maxpool2, LDS-tiled (unchanged from R4).
__global__ __launch_bounds__(256) void k_conv2t(const float* __restrict__ h1,
                                                const float* __restrict__ w2,
                                                const float* __restrict__ b2,
                                                float* __restrict__ h2) {
    __shared__ float s_in[16 * 324];

    int tid = threadIdx.x;
    int n  = blockIdx.x >> 6;
    int tile = blockIdx.x & 63;
    int cx0 = (tile & 7) << 4;
    int cy0 = (tile >> 3) << 4;

    const float* hb = h1 + ((size_t)(n * 16) << 14);
    for (int e = tid; e < 5184; e += 256) {
        int cin = e / 324;
        int rem = e - cin * 324;
        int r = rem / 18;
        int c = rem - r * 18;
        int iy = cy0 - 1 + r, ix = cx0 - 1 + c;
        float v = 0.0f;
        if (iy >= 0 && iy < 128 && ix >= 0 && ix < 128)
            v = hb[((size_t)cin << 14) + iy * 128 + ix];
        s_in[e] = v;
    }
    __syncthreads();

    int lx  = tid & 15;
    int lyq = tid >> 4;

    float v[32];
#pragma unroll
    for (int c = 0; c < 32; c++) v[c] = b2[c];

    for (int cin = 0; cin < 16; cin++) {
        float p[9];
        const float* sp = s_in + cin * 324 + lyq * 18 + lx;
#pragma unroll
        for (int ky = 0; ky < 3; ky++)
#pragma unroll
            for (int kx = 0; kx < 3; kx++)
                p[ky * 3 + kx] = sp[ky * 18 + kx];
        const float* wb = w2 + cin * 9;
#pragma unroll
        for (int c = 0; c < 32; c++) {
            float a = v[c];
#pragma unroll
            for (int t = 0; t < 9; t++) a += wb[c * 144 + t] * p[t];
            v[c] = a;
        }
    }

    bool active = ((lx & 1) == 0) && ((lyq & 1) == 0);
    int px = (cx0 >> 1) + (lx >> 1);
    int py = (cy0 >> 1) + (lyq >> 1);
    float* ob = h2 + ((size_t)(n * 32) << 12) + (py << 6) + px;
#pragma unroll
    for (int c = 0; c < 32; c++) {
        float m = v[c];
        m = fmaxf(m, __shfl_xor(m, 1));
        m = fmaxf(m, __shfl_xor(m, 16));
        if (active) ob[(size_t)c << 12] = m;
    }
}

// VQ via split-bf16 MFMA. Block = 256 threads (4 waves) = 256 positions.
// grid = 1024. q written in-place over h2.
__global__ __launch_bounds__(256) void k_vq_mfma(const float* __restrict__ h2,
                                                 const float* __restrict__ cb,
                                                 float* __restrict__ q,
                                                 float* __restrict__ idx_out,
                                                 float* __restrict__ loss_out,
                                                 int* __restrict__ nflag,
                                                 int* __restrict__ flags) {
    __shared__ unsigned short cbhi[512 * 36];  // stride 36 bf16 (72B, 8B-aligned)
    __shared__ unsigned short cblo[512 * 36];
    __shared__ float c2s[512];
    __shared__ float s_best[256], s_best2[256];
    __shared__ int   s_bi[256];
    __shared__ float wsum[4];

    int tid = threadIdx.x;

    // stage codebook as bf16 hi/lo + c2 (fp32)
    for (int k = tid; k < 512; k += 256) {
        const float4* row = (const float4*)(cb + k * 32);
        float c2 = 0.0f;
#pragma unroll
        for (int j = 0; j < 8; j++) {
            float4 f4 = row[j];
            float fv[4] = {f4.x, f4.y, f4.z, f4.w};
#pragma unroll
            for (int e = 0; e < 4; e++) {
                float fe = fv[e];
                c2 += fe * fe;
                unsigned short hi = f2bf(fe);
                unsigned short lo = f2bf(fe - bf2f(hi));
                cbhi[k * 36 + j * 4 + e] = hi;
                cblo[k * 36 + j * 4 + e] = lo;
            }
        }
        c2s[k] = c2;
    }
    __syncthreads();

    int lane = tid & 63;
    int wid  = tid >> 6;
    int m    = lane & 15;
    int quad = lane >> 4;

    int img = blockIdx.x >> 4;                 // 16 blocks per image
    int sp0 = (blockIdx.x & 15) << 8;          // 256 positions within image
    const float* xb = h2 + ((size_t)(img * 32) << 12) + sp0;

    // A fragments for 4 m-tiles (wave's 64 positions), plus per-row x2
    short8 Ahi[4], Alo[4];
    float x2r[4][4];
    float x2own[4];
#pragma unroll
    for (int mt = 0; mt < 4; mt++) {
        const float* xp = xb + wid * 64 + mt * 16 + m;
        float x2 = 0.0f;
#pragma unroll
        for (int j = 0; j < 8; j++) {
            float fe = xp[(size_t)(quad * 8 + j) << 12];
            x2 += fe * fe;
            unsigned short hi = f2bf(fe);
            unsigned short lo = f2bf(fe - bf2f(hi));
            Ahi[mt][j] = (short)hi;
            Alo[mt][j] = (short)lo;
        }
        x2 += __shfl_xor(x2, 16);
        x2 += __shfl_xor(x2, 32);
        x2own[mt] = x2;   // full x2 of row m for m-tile mt
    }
#pragma unroll
    for (int mt = 0; mt < 4; mt++)
#pragma unroll
        for (int r = 0; r < 4; r++)
            x2r[mt][r] = __shfl(x2own[mt], quad * 4 + r);

    float best[4][4], best2[4][4];
    int bi[4][4];
#pragma unroll
    for (int mt = 0; mt < 4; mt++)
#pragma unroll
        for (int r = 0; r < 4; r++) {
            best[mt][r] = INFINITY; best2[mt][r] = INFINITY; bi[mt][r] = 0;
        }

    for (int nt = 0; nt < 32; nt++) {
        int ncode = nt * 16 + m;   // this lane's column code
        // B fragments (shared across m-tiles): two b64 reads each
        short8 Bhi, Blo;
        {
            const short4v* p0 = (const short4v*)&cbhi[ncode * 36 + quad * 8];
            const short4v* p1 = (const short4v*)&cblo[ncode * 36 + quad * 8];
            short4v h0 = p0[0], h1v = p0[1], l0 = p1[0], l1 = p1[1];
#pragma unroll
            for (int e = 0; e < 4; e++) {
                Bhi[e] = h0[e]; Bhi[e + 4] = h1v[e];
                Blo[e] = l0[e]; Blo[e + 4] = l1[e];
            }
        }
        float c2v = c2s[ncode];

        float4v acc[4];
#pragma unroll
        for (int mt = 0; mt < 4; mt++) {
            float4v z = {0.0f, 0.0f, 0.0f, 0.0f};
            z = __builtin_amdgcn_mfma_f32_16x16x32_bf16(Alo[mt], Bhi, z, 0, 0, 0);
            z = __builtin_amdgcn_mfma_f32_16x16x32_bf16(Ahi[mt], Blo, z, 0, 0, 0);
            z = __builtin_amdgcn_mfma_f32_16x16x32_bf16(Ahi[mt], Bhi, z, 0, 0, 0);
            acc[mt] = z;
        }
#pragma unroll
        for (int mt = 0; mt < 4; mt++)
#pragma unroll
            for (int r = 0; r < 4; r++) {
                float dist = fmaf(acc[mt][r], -2.0f, x2r[mt][r] + c2v);
                best2[mt][r] = fminf(best2[mt][r], fmaxf(dist, best[mt][r]));
                bool lt = dist < best[mt][r];
                bi[mt][r] = lt ? ncode : bi[mt][r];
                best[mt][r] = fminf(best[mt][r], dist);
            }
    }

    // reduce across the 16 column-lanes of each quad
#pragma unroll
    for (int mt = 0; mt < 4; mt++)
#pragma unroll
        for (int r = 0; r < 4; r++) {
            float b1v = best[mt][r], b2v = best2[mt][r];
            int   biv = bi[mt][r];
#pragma unroll
            for (int mask = 1; mask < 16; mask <<= 1) {
                float ob = __shfl_xor(b1v, mask);
                float ob2 = __shfl_xor(b2v, mask);
                int   obi = __shfl_xor(biv, mask);
                b2v = fminf(fminf(b2v, ob2), fmaxf(b1v, ob));
                if (ob < b1v || (ob == b1v && obi < biv)) { b1v = ob; biv = obi; }
            }
            if (m == 0) {
                int p = wid * 64 + mt * 16 + quad * 4 + r;
                s_best[p] = b1v; s_best2[p] = b2v; s_bi[p] = biv;
            }
        }
    __syncthreads();

    // epilogue: thread t owns position t
    int pos = blockIdx.x * 256 + tid;
    float bb = s_best[tid], bb2 = s_best2[tid];
    int   kk = s_bi[tid];
    idx_out[pos] = (float)kk;

    float eps = 0.05f + 0.002f * fabsf(bb);
    if (bb2 - bb < eps) {
        int slot = atomicAdd(nflag, 1);
        if (slot < MAXFLAG) flags[slot] = pos;
    }

    // gather exact fp32 codebook row -> q (in-place over h2)
    const float4* crow = (const float4*)(cb + kk * 32);
    float* qp = q + ((size_t)(img * 32) << 12) + sp0 + tid;
#pragma unroll
    for (int j = 0; j < 8; j++) {
        float4 f4 = crow[j];
        qp[(size_t)(j * 4 + 0) << 12] = f4.x;
        qp[(size_t)(j * 4 + 1) << 12] = f4.y;
        qp[(size_t)(j * 4 + 2) << 12] = f4.z;
        qp[(size_t)(j * 4 + 3) << 12] = f4.w;
    }

    float lsum = fmaxf(bb, 0.0f);
#pragma unroll
    for (int o = 32; o > 0; o >>= 1) lsum += __shfl_down(lsum, o);
    if (lane == 0) wsum[wid] = lsum;
    __syncthreads();
    if (tid == 0)
        atomicAdd(loss_out, (wsum[0] + wsum[1] + wsum[2] + wsum[3]) * (1.0f / 8388608.0f));
}

// fp64 repair: one wave per flagged position (unchanged).
__global__ __launch_bounds__(64) void k_repair(const float* __restrict__ x,
                                               const float* __restrict__ w1,
                                               const float* __restrict__ b1,
                                               const float* __restrict__ w2,
                                               const float* __restrict__ b2,
                                               const float* __restrict__ cb,
                                               float* __restrict__ q,
                                               float* __restrict__ idx_out,
                                               const int* __restrict__ nflag,
                                               const int* __restrict__ flags) {
    __shared__ double h1w[16][16];
    __shared__ double xvd[32];
    int lane = threadIdx.x;
    int cnt = *nflag;
    if (cnt > MAXFLAG) cnt = MAXFLAG;

    for (int fi = blockIdx.x; fi < cnt; fi += gridDim.x) {
        int pos = flags[fi];
        int n = pos >> 12, sp = pos & 4095, yo = sp >> 6, xo = sp & 63;

        int pix = lane >> 2, cg = lane & 3;
        int dy = pix >> 2, dx = pix & 3;
        int yh = 2 * yo - 1 + dy, xh = 2 * xo - 1 + dx;
        double hv[4] = {0.0, 0.0, 0.0, 0.0};
        if (yh >= 0 && yh < 128 && xh >= 0 && xh < 128) {
            const float* xin = x + (size_t)n * 65536;
            double patch[4][4];
            int y0 = 2 * yh - 1, x0 = 2 * xh - 1;
#pragma unroll
            for (int i = 0; i < 4; i++) {
                int iy = y0 + i;
                bool oy = (iy >= 0 && iy < 256);
#pragma unroll
                for (int j = 0; j < 4; j++) {
                    int ix = x0 + j;
                    patch[i][j] = (oy && ix >= 0 && ix < 256) ? (double)xin[iy * 256 + ix] : 0.0;
                }
            }
#pragma unroll
            for (int j = 0; j < 4; j++) {
                int c = cg * 4 + j;
                double mm = -INFINITY;
#pragma unroll
                for (int sy = 0; sy < 2; sy++)
#pragma unroll
                    for (int sx = 0; sx < 2; sx++) {
                        double acc = (double)b1[c];
#pragma unroll
                        for (int ky = 0; ky < 3; ky++)
#pragma unroll
                            for (int kx = 0; kx < 3; kx++)
                                acc += (double)w1[c * 9 + ky * 3 + kx] * patch[sy + ky][sx + kx];
                        mm = fmax(mm, acc);
                    }
                hv[j] = 0.5 * mm * (1.0 + erf(mm * 0.70710678118654752440));
            }
        }
        __syncthreads();
#pragma unroll
        for (int j = 0; j < 4; j++) h1w[cg * 4 + j][pix] = hv[j];
        __syncthreads();

        if (lane < 32) {
            double bb = (double)b2[lane];
            double acc[2][2] = {{bb, bb}, {bb, bb}};
            for (int cin = 0; cin < 16; cin++)
#pragma unroll
                for (int ky = 0; ky < 3; ky++)
#pragma unroll
                    for (int kx = 0; kx < 3; kx++) {
                        double wv = (double)w2[((lane * 16 + cin) * 3 + ky) * 3 + kx];
#pragma unroll
                        for (int sy = 0; sy < 2; sy++)
#pragma unroll
                            for (int sx = 0; sx < 2; sx++)
                                acc[sy][sx] += wv * h1w[cin][(sy + ky) * 4 + (sx + kx)];
                    }
            xvd[lane] = fmax(fmax(acc[0][0], acc[0][1]), fmax(acc[1][0], acc[1][1]));
        }
        __syncthreads();

        double x2 = 0.0;
        for (int d = 0; d < 32; d++) x2 += xvd[d] * xvd[d];
        double best = INFINITY;
        int bi = 0;
        for (int j = 0; j < 8; j++) {
            int k = lane * 8 + j;
            const float* cp = cb + k * 32;
            double c2 = 0.0, dot = 0.0;
#pragma unroll
            for (int d = 0; d < 32; d++) {
                double cd = (double)cp[d];
                c2 += cd * cd;
                dot += xvd[d] * cd;
            }
            double dist = x2 - 2.0 * dot + c2;
            if (dist < best) { best = dist; bi = k; }
        }
#pragma unroll
        for (int o = 32; o > 0; o >>= 1) {
            double od = __shfl_down(best, o);
            int oi = __shfl_down(bi, o);
            if (od < best || (od == best && oi < bi)) { best = od; bi = oi; }
        }
        bi = __shfl(bi, 0);

        if (lane == 0) idx_out[(size_t)n * 4096 + sp] = (float)bi;
        if (lane < 32) q[((size_t)(n * 32 + lane) << 12) + sp] = cb[bi * 32 + lane];
    }
}

// prep: parity-combined decoder weights (unchanged).
__global__ __launch_bounds__(256) void k_prep(const float* __restrict__ w3,
                                              const float* __restrict__ w4,
                                              float* __restrict__ wc3,
                                              float* __restrict__ wc4) {
    const int masks[2][2] = {{1, 6}, {3, 4}};
    for (int e = threadIdx.x; e < 8192; e += 256) {
        int cout = e & 15, tap = (e >> 4) & 3, cin = (e >> 6) & 31, pp = e >> 11;
        int rm = masks[pp >> 1][tap >> 1], cm = masks[pp & 1][tap & 1];
        float s = 0.0f;
        for (int ky = 0; ky < 3; ky++)
            if ((rm >> ky) & 1)
                for (int kx = 0; kx < 3; kx++)
                    if ((cm >> kx) & 1) s += w3[(cout * 32 + cin) * 9 + ky * 3 + kx];
        wc3[e] = s;
    }
    for (int e = threadIdx.x; e < 1024; e += 256) {
        int tap = e & 3, cin = (e >> 2) & 15, pp = e >> 6;
        int rm = masks[pp >> 1][tap >> 1], cm = masks[pp & 1][tap & 1];
        float s = 0.0f;
        for (int ky = 0; ky < 3; ky++)
            if ((rm >> ky) & 1)
                for (int kx = 0; kx < 3; kx++)
                    if ((cm >> kx) & 1) s += w4[cin * 9 + ky * 3 + kx];
        wc4[e] = s;
    }
}

// up2+conv3(32->16)+gelu, parity-collapsed (unchanged).
__global__ __launch_bounds__(256) void k_conv3n(const float* __restrict__ q,
                                                const float* __restrict__ wc3,
                                                const float* __restrict__ b3,
                                                float* __restrict__ h3) {
    int t = blockIdx.x * 256 + threadIdx.x;
    int b = t & 63, a = (t >> 6) & 63, n = t >> 12;

    float acc[2][2][16];
#pragma unroll
    for (int c = 0; c < 16; c++) {
        float bv = b3[c];
        acc[0][0][c] = bv; acc[0][1][c] = bv; acc[1][0][c] = bv; acc[1][1][c] = bv;
    }

    for (int cin = 0; cin < 32; cin++) {
        const float* qc = q + ((size_t)(n * 32 + cin) << 12);
        float v[3][3];
#pragma unroll
        for (int r = 0; r < 3; r++) {
            int qy = a - 1 + r;
            bool vy = (qy >= 0 && qy < 64);
#pragma unroll
            for (int cc = 0; cc < 3; cc++) {
                int qx = b - 1 + cc;
                v[r][cc] = (vy && qx >= 0 && qx < 64) ? qc[(qy << 6) + qx] : 0.0f;
            }
        }
        const float* wp = wc3 + cin * 64;
#pragma unroll
        for (int py = 0; py < 2; py++)
#pragma unroll
            for (int px = 0; px < 2; px++) {
                const float* wpp = wp + (py * 2 + px) * 2048;
#pragma unroll
                for (int dy = 0; dy < 2; dy++)
#pragma unroll
                    for (int dx = 0; dx < 2; dx++) {
                        float vv = v[py + dy][px + dx];
                        const float* wt = wpp + (dy * 2 + dx) * 16;
#pragma unroll
                        for (int c = 0; c < 16; c++)
                            acc[py][px][c] += wt[c] * vv;
                    }
            }
    }
#pragma unroll
    for (int c = 0; c < 16; c++)
#pragma unroll
        for (int py = 0; py < 2; py++) {
            float2 f2 = make_float2(GELUF(acc[py][0][c]), GELUF(acc[py][1][c]));
            *(float2*)(h3 + ((size_t)(n * 16 + c) << 14) + ((2 * a + py) << 7) + 2 * b) = f2;
        }
}

// up2+conv4(16->1)+clip, parity-collapsed (unchanged).
__global__ __launch_bounds__(256) void k_conv4n(const float* __restrict__ h3,
                                                const float* __restrict__ wc4,
                                                const float* __restrict__ b4,
                                                float* __restrict__ out) {
    int t = blockIdx.x * 256 + threadIdx.x;
    int b = t & 127, a = (t >> 7) & 127, n = t >> 14;

    float bv = b4[0];
    float acc[2][2] = {{bv, bv}, {bv, bv}};

    for (int cin = 0; cin < 16; cin++) {
        const float* hc = h3 + ((size_t)(n * 16 + cin) << 14);
        float v[3][3];
#pragma unroll
        for (int r = 0; r < 3; r++) {
            int hy = a - 1 + r;
            bool vy = (hy >= 0 && hy < 128);
#pragma unroll
            for (int cc = 0; cc < 3; cc++) {
                int hx = b - 1 + cc;
                v[r][cc] = (vy && hx >= 0 && hx < 128) ? hc[(hy << 7) + hx] : 0.0f;
            }
        }
#pragma unroll
        for (int py = 0; py < 2; py++)
#pragma unroll
            for (int px = 0; px < 2; px++)
#pragma unroll
                for (int dy = 0; dy < 2; dy++)
#pragma unroll
                    for (int dx = 0; dx < 2; dx++)
                        acc[py][px] += wc4[(py * 2 + px) * 64 + cin * 4 + dy * 2 + dx] *
                                       v[py + dy][px + dx];
    }
#pragma unroll
    for (int py = 0; py < 2; py++) {
        float2 f2 = make_float2(fminf(fmaxf(acc[py][0], -1.0f), 1.0f),
                                fminf(fmaxf(acc[py][1], -1.0f), 1.0f));
        *(float2*)(out + (size_t)n * 65536 + (2 * a + py) * 256 + 2 * b) = f2;
    }
}

extern "C" void kernel_launch(void* const* d_in, const int* in_sizes, int n_in,
                              void* d_out, int out_size, void* d_ws, size_t ws_size,
                              hipStream_t stream) {
    const float* x  = (const float*)d_in[0];
    const float* w1 = (const float*)d_in[1];
    const float* b1 = (const float*)d_in[2];
    const float* w2 = (const float*)d_in[3];
    const float* b2 = (const float*)d_in[4];
    const float* cb = (const float*)d_in[5];
    const float* w3 = (const float*)d_in[6];
    const float* b3 = (const float*)d_in[7];
    const float* w4 = (const float*)d_in[8];
    const float* b4 = (const float*)d_in[9];

    float* out      = (float*)d_out;
    float* idx_out  = out + 4194304;
    float* loss_out = out + 4194304 + 262144;

    char* ws = (char*)d_ws;
    float* h1  = (float*)ws;                           // [0,64M) -> later h3
    float* h2  = (float*)(ws + (size_t)67108864);      // [64M,96M), q in-place
    float* h3  = (float*)ws;
    float* wc3 = (float*)(ws + (size_t)100663296);     // 32 KB
    float* wc4 = wc3 + 8192;                           // 4 KB
    int*   nflag = (int*)(ws + (size_t)100663296 + 36864);
    int*   flags = nflag + 16;                         // 256 KB

    (void)hipMemsetAsync(loss_out, 0, 4, stream);
    (void)hipMemsetAsync(nflag, 0, 4, stream);

    k_prep<<<1, 256, 0, stream>>>(w3, w4, wc3, wc4);
    k_conv1<<<4096, 256, 0, stream>>>(x, w1, b1, h1);
    k_conv2t<<<4096, 256, 0, stream>>>(h1, w2, b2, h2);
    k_vq_mfma<<<1024, 256, 0, stream>>>(h2, cb, h2, idx_out, loss_out, nflag, flags);
    k_repair<<<4096, 64, 0, stream>>>(x, w1, b1, w2, b2, cb, h2, idx_out, nflag, flags);
    k_conv3n<<<1024, 256, 0, stream>>>(h2, wc3, b3, h3);
    k_conv4n<<<4096, 256, 0, stream>>>(h3, wc4, b4, out);
}

// Round 7
// 593.712 us; speedup vs baseline: 2.9758x; 1.3304x over previous
//
#include <hip/hip_runtime.h>
#include <math.h>

// ---------------------------------------------------------------------------
// SimpleVQAutoEncoder forward.
// conv1 -> h1 as split-bf16 hi/lo, layout [n][y][x][cin] (coalesced).
// conv2: split-bf16 MFMA GEMM over (tap,cin) K=144 (5 K-steps of 32),
//   in-register maxpool from MFMA C-layout, bias post-max.
// VQ: split-bf16 MFMA distances + near-tie flagging; fp64 repair pass
//   recomputes full encoder chain for flagged positions (indices == numpy).
// Decoder: parity-collapsed 2x2 convs.
// Outputs d_out (fp32): recon 4194304 | indices 262144 | loss 1
// ---------------------------------------------------------------------------

#define GELUF(v) (0.5f * (v) * (1.0f + erff((v) * 0.70710678118654752440f)))
#define MAXFLAG 65536

typedef __attribute__((ext_vector_type(8))) short short8;
typedef __attribute__((ext_vector_type(4))) short short4v;
typedef __attribute__((ext_vector_type(4))) float float4v;

static __device__ inline unsigned short f2bf(float f) {
    unsigned u = __float_as_uint(f);
    unsigned r = (u + 0x7FFFu + ((u >> 16) & 1u)) >> 16;
    return (unsigned short)r;
}
static __device__ inline float bf2f(unsigned short h) {
    return __uint_as_float(((unsigned)h) << 16);
}

// conv1 (1->16) + maxpool2 + gelu; output split-bf16 hi/lo [n][y][x][cin].
__global__ __launch_bounds__(256) void k_conv1b(const float* __restrict__ x,
                                                const float* __restrict__ w1,
                                                const float* __restrict__ b1,
                                                unsigned short* __restrict__ h1h,
                                                unsigned short* __restrict__ h1l) {
    int idx = blockIdx.x * 256 + threadIdx.x;
    int xo = idx & 127;
    int yo = (idx >> 7) & 127;
    int n  = idx >> 14;
    const float* xin = x + (size_t)n * 65536;

    float patch[4][4];
    int y0 = 2 * yo - 1, x0 = 2 * xo - 1;
#pragma unroll
    for (int i = 0; i < 4; i++) {
        int iy = y0 + i;
        bool oy = (iy >= 0 && iy < 256);
#pragma unroll
        for (int j = 0; j < 4; j++) {
            int ix = x0 + j;
            patch[i][j] = (oy && ix >= 0 && ix < 256) ? xin[iy * 256 + ix] : 0.0f;
        }
    }
    unsigned short hi[16], lo[16];
#pragma unroll
    for (int c = 0; c < 16; c++) {
        float m = -INFINITY;
#pragma unroll
        for (int sy = 0; sy < 2; sy++)
#pragma unroll
            for (int sx = 0; sx < 2; sx++) {
                float acc = b1[c];
#pragma unroll
                for (int ky = 0; ky < 3; ky++)
#pragma unroll
                    for (int kx = 0; kx < 3; kx++)
                        acc += w1[c * 9 + ky * 3 + kx] * patch[sy + ky][sx + kx];
                m = fmaxf(m, acc);
            }
        float g = GELUF(m);
        hi[c] = f2bf(g);
        lo[c] = f2bf(g - bf2f(hi[c]));
    }
    size_t off = ((size_t)idx) << 4;  // *16 shorts
    uint ph[8], pl[8];
#pragma unroll
    for (int c2 = 0; c2 < 8; c2++) {
        ph[c2] = (uint)hi[2 * c2] | ((uint)hi[2 * c2 + 1] << 16);
        pl[c2] = (uint)lo[2 * c2] | ((uint)lo[2 * c2 + 1] << 16);
    }
    uint4* dh = (uint4*)(h1h + off);
    uint4* dl = (uint4*)(h1l + off);
    dh[0] = make_uint4(ph[0], ph[1], ph[2], ph[3]);
    dh[1] = make_uint4(ph[4], ph[5], ph[6], ph[7]);
    dl[0] = make_uint4(pl[0], pl[1], pl[2], pl[3]);
    dl[1] = make_uint4(pl[4], pl[5], pl[6], pl[7]);
}

// conv2 (16->32) + maxpool2 via split-bf16 MFMA. Block = 16x16 conv positions.
// K = (tap,cin) in 5 steps of 32 (2 taps x 16 cin; tap9 = zero weights).
// Wave w: m-tiles = conv rows 4w..4w+3, 16 x-positions each; nt = cout halves.
__global__ __launch_bounds__(256) void k_conv2m(const unsigned short* __restrict__ h1h,
                                                const unsigned short* __restrict__ h1l,
                                                const unsigned short* __restrict__ w2h,
                                                const unsigned short* __restrict__ w2l,
                                                const float* __restrict__ b2,
                                                float* __restrict__ h2) {
    __shared__ unsigned short s_hi[18 * 2 * 18 * 8];  // unit=(r*2+half)*18+c
    __shared__ unsigned short s_lo[18 * 2 * 18 * 8];
    __shared__ unsigned short s_wh[32 * 10 * 2 * 8];  // unit=(cout*10+tap)*2+half
    __shared__ unsigned short s_wl[32 * 10 * 2 * 8];
    __shared__ float s_pool[32 * 64];                 // [cout][py*8+px]

    int tid = threadIdx.x;
    int n = blockIdx.x >> 6;
    int tile = blockIdx.x & 63;
    int cx0 = (tile & 7) << 4, cy0 = (tile >> 3) << 4;

    // stage weights (pre-split by k_prep, exact LDS layout)
    {
        const uint* gh = (const uint*)w2h;
        const uint* gl = (const uint*)w2l;
        uint* dh = (uint*)s_wh; uint* dl = (uint*)s_wl;
        for (int e = tid; e < 2560; e += 256) { dh[e] = gh[e]; dl[e] = gl[e]; }
    }
    // stage 18x18x16 input window
    {
        const uint* gh = (const uint*)(h1h + (((size_t)n) << 18));  // n*128*128*16 shorts
        const uint* gl = (const uint*)(h1l + (((size_t)n) << 18));
        uint* dh = (uint*)s_hi; uint* dl = (uint*)s_lo;
        for (int e = tid; e < 2592; e += 256) {
            int r = e / 144;
            int rem = e - r * 144;
            int c = rem >> 3;
            int dw = rem & 7;
            int y = cy0 - 1 + r, xx = cx0 - 1 + c;
            uint vh = 0, vl = 0;
            if (y >= 0 && y < 128 && xx >= 0 && xx < 128) {
                size_t g = ((size_t)((y << 7) + xx) << 3) + dw;
                vh = gh[g]; vl = gl[g];
            }
            int half = dw >> 2;
            int du = (((r * 2 + half) * 18 + c) << 2) + (dw & 3);
            dh[du] = vh; dl[du] = vl;
        }
    }
    __syncthreads();

    int lane = tid & 63, wid = tid >> 6;
    int m = lane & 15, quad = lane >> 4;
    int tl = quad >> 1, half = quad & 1;

    float4v acc[4][2];
#pragma unroll
    for (int mt = 0; mt < 4; mt++)
#pragma unroll
        for (int nt = 0; nt < 2; nt++)
            acc[mt][nt] = (float4v){0.0f, 0.0f, 0.0f, 0.0f};

    for (int s = 0; s < 5; s++) {
        int tA = (s < 4) ? (2 * s + tl) : 8;          // A-side tap (dummy ok for pad)
        int tB = (s < 4) ? (2 * s + tl) : (8 + tl);   // B-side tap (9 = zeros)
        short8 Bh[2], Bl[2];
#pragma unroll
        for (int nt = 0; nt < 2; nt++) {
            int u = ((nt * 16 + m) * 10 + tB) * 2 + half;
            Bh[nt] = *(const short8*)(s_wh + (u << 3));
            Bl[nt] = *(const short8*)(s_wl + (u << 3));
        }
        int ky = tA / 3, kx = tA - 3 * (tA / 3);
        short8 Ah[4], Al[4];
#pragma unroll
        for (int mt = 0; mt < 4; mt++) {
            int u = (((wid * 4 + mt + ky) * 2 + half) * 18) + m + kx;
            Ah[mt] = *(const short8*)(s_hi + (u << 3));
            Al[mt] = *(const short8*)(s_lo + (u << 3));
        }
#pragma unroll
        for (int mt = 0; mt < 4; mt++)
#pragma unroll
            for (int nt = 0; nt < 2; nt++) {
                float4v z = acc[mt][nt];
                z = __builtin_amdgcn_mfma_f32_16x16x32_bf16(Al[mt], Bh[nt], z, 0, 0, 0);
                z = __builtin_amdgcn_mfma_f32_16x16x32_bf16(Ah[mt], Bl[nt], z, 0, 0, 0);
                z = __builtin_amdgcn_mfma_f32_16x16x32_bf16(Ah[mt], Bh[nt], z, 0, 0, 0);
                acc[mt][nt] = z;
            }
    }

    // in-register 2x2 maxpool: x-pairs = reg pairs, y-pairs = mt pairs
#pragma unroll
    for (int nt = 0; nt < 2; nt++) {
        int cout = nt * 16 + m;
        float bias = b2[cout];
#pragma unroll
        for (int mtp = 0; mtp < 2; mtp++) {
            float4v a0 = acc[2 * mtp][nt], a1 = acc[2 * mtp + 1][nt];
            float p0 = fmaxf(fmaxf(a0[0], a0[1]), fmaxf(a1[0], a1[1])) + bias;
            float p1 = fmaxf(fmaxf(a0[2], a0[3]), fmaxf(a1[2], a1[3])) + bias;
            int py = wid * 2 + mtp;
            int px = quad * 2;
            s_pool[cout * 64 + py * 8 + px]     = p0;
            s_pool[cout * 64 + py * 8 + px + 1] = p1;
        }
    }
    __syncthreads();
    {
        int c = tid >> 3, pr = tid & 7;
        float* dst = h2 + (((size_t)(n * 32 + c)) << 12) + ((cy0 >> 1) + pr) * 64 + (cx0 >> 1);
        const float4* src = (const float4*)(s_pool + c * 64 + pr * 8);
        ((float4*)dst)[0] = src[0];
        ((float4*)dst)[1] = src[1];
    }
}

// VQ via split-bf16 MFMA (unchanged from R6, validated).
__global__ __launch_bounds__(256) void k_vq_mfma(const float* __restrict__ h2,
                                                 const float* __restrict__ cb,
                                                 float* __restrict__ q,
                                                 float* __restrict__ idx_out,
                                                 float* __restrict__ loss_out,
                                                 int* __restrict__ nflag,
                                                 int* __restrict__ flags) {
    __shared__ unsigned short cbhi[512 * 36];
    __shared__ unsigned short cblo[512 * 36];
    __shared__ float c2s[512];
    __shared__ float s_best[256], s_best2[256];
    __shared__ int   s_bi[256];
    __shared__ float wsum[4];

    int tid = threadIdx.x;

    for (int k = tid; k < 512; k += 256) {
        const float4* row = (const float4*)(cb + k * 32);
        float c2 = 0.0f;
#pragma unroll
        for (int j = 0; j < 8; j++) {
            float4 f4 = row[j];
            float fv[4] = {f4.x, f4.y, f4.z, f4.w};
#pragma unroll
            for (int e = 0; e < 4; e++) {
                float fe = fv[e];
                c2 += fe * fe;
                unsigned short hi = f2bf(fe);
                unsigned short lo = f2bf(fe - bf2f(hi));
                cbhi[k * 36 + j * 4 + e] = hi;
                cblo[k * 36 + j * 4 + e] = lo;
            }
        }
        c2s[k] = c2;
    }
    __syncthreads();

    int lane = tid & 63;
    int wid  = tid >> 6;
    int m    = lane & 15;
    int quad = lane >> 4;

    int img = blockIdx.x >> 4;
    int sp0 = (blockIdx.x & 15) << 8;
    const float* xb = h2 + ((size_t)(img * 32) << 12) + sp0;

    short8 Ahi[4], Alo[4];
    float x2r[4][4];
    float x2own[4];
#pragma unroll
    for (int mt = 0; mt < 4; mt++) {
        const float* xp = xb + wid * 64 + mt * 16 + m;
        float x2 = 0.0f;
#pragma unroll
        for (int j = 0; j < 8; j++) {
            float fe = xp[(size_t)(quad * 8 + j) << 12];
            x2 += fe * fe;
            unsigned short hi = f2bf(fe);
            unsigned short lo = f2bf(fe - bf2f(hi));
            Ahi[mt][j] = (short)hi;
            Alo[mt][j] = (short)lo;
        }
        x2 += __shfl_xor(x2, 16);
        x2 += __shfl_xor(x2, 32);
        x2own[mt] = x2;
    }
#pragma unroll
    for (int mt = 0; mt < 4; mt++)
#pragma unroll
        for (int r = 0; r < 4; r++)
            x2r[mt][r] = __shfl(x2own[mt], quad * 4 + r);

    float best[4][4], best2[4][4];
    int bi[4][4];
#pragma unroll
    for (int mt = 0; mt < 4; mt++)
#pragma unroll
        for (int r = 0; r < 4; r++) {
            best[mt][r] = INFINITY; best2[mt][r] = INFINITY; bi[mt][r] = 0;
        }

    for (int nt = 0; nt < 32; nt++) {
        int ncode = nt * 16 + m;
        short8 Bhi, Blo;
        {
            const short4v* p0 = (const short4v*)&cbhi[ncode * 36 + quad * 8];
            const short4v* p1 = (const short4v*)&cblo[ncode * 36 + quad * 8];
            short4v h0 = p0[0], h1v = p0[1], l0 = p1[0], l1 = p1[1];
#pragma unroll
            for (int e = 0; e < 4; e++) {
                Bhi[e] = h0[e]; Bhi[e + 4] = h1v[e];
                Blo[e] = l0[e]; Blo[e + 4] = l1[e];
            }
        }
        float c2v = c2s[ncode];

        float4v acc[4];
#pragma unroll
        for (int mt = 0; mt < 4; mt++) {
            float4v z = {0.0f, 0.0f, 0.0f, 0.0f};
            z = __builtin_amdgcn_mfma_f32_16x16x32_bf16(Alo[mt], Bhi, z, 0, 0, 0);
            z = __builtin_amdgcn_mfma_f32_16x16x32_bf16(Ahi[mt], Blo, z, 0, 0, 0);
            z = __builtin_amdgcn_mfma_f32_16x16x32_bf16(Ahi[mt], Bhi, z, 0, 0, 0);
            acc[mt] = z;
        }
#pragma unroll
        for (int mt = 0; mt < 4; mt++)
#pragma unroll
            for (int r = 0; r < 4; r++) {
                float dist = fmaf(acc[mt][r], -2.0f, x2r[mt][r] + c2v);
                best2[mt][r] = fminf(best2[mt][r], fmaxf(dist, best[mt][r]));
                bool lt = dist < best[mt][r];
                bi[mt][r] = lt ? ncode : bi[mt][r];
                best[mt][r] = fminf(best[mt][r], dist);
            }
    }

#pragma unroll
    for (int mt = 0; mt < 4; mt++)
#pragma unroll
        for (int r = 0; r < 4; r++) {
            float b1v = best[mt][r], b2v = best2[mt][r];
            int   biv = bi[mt][r];
#pragma unroll
            for (int mask = 1; mask < 16; mask <<= 1) {
                float ob = __shfl_xor(b1v, mask);
                float ob2 = __shfl_xor(b2v, mask);
                int   obi = __shfl_xor(biv, mask);
                b2v = fminf(fminf(b2v, ob2), fmaxf(b1v, ob));
                if (ob < b1v || (ob == b1v && obi < biv)) { b1v = ob; biv = obi; }
            }
            if (m == 0) {
                int p = wid * 64 + mt * 16 + quad * 4 + r;
                s_best[p] = b1v; s_best2[p] = b2v; s_bi[p] = biv;
            }
        }
    __syncthreads();

    int pos = blockIdx.x * 256 + tid;
    float bb = s_best[tid], bb2 = s_best2[tid];
    int   kk = s_bi[tid];
    idx_out[pos] = (float)kk;

    float eps = 0.05f + 0.002f * fabsf(bb);
    if (bb2 - bb < eps) {
        int slot = atomicAdd(nflag, 1);
        if (slot < MAXFLAG) flags[slot] = pos;
    }

    const float4* crow = (const float4*)(cb + kk * 32);
    float* qp = q + ((size_t)(img * 32) << 12) + sp0 + tid;
#pragma unroll
    for (int j = 0; j < 8; j++) {
        float4 f4 = crow[j];
        qp[(size_t)(j * 4 + 0) << 12] = f4.x;
        qp[(size_t)(j * 4 + 1) << 12] = f4.y;
        qp[(size_t)(j * 4 + 2) << 12] = f4.z;
        qp[(size_t)(j * 4 + 3) << 12] = f4.w;
    }

    float lsum = fmaxf(bb, 0.0f);
#pragma unroll
    for (int o = 32; o > 0; o >>= 1) lsum += __shfl_down(lsum, o);
    if (lane == 0) wsum[wid] = lsum;
    __syncthreads();
    if (tid == 0)
        atomicAdd(loss_out, (wsum[0] + wsum[1] + wsum[2] + wsum[3]) * (1.0f / 8388608.0f));
}

// fp64 repair: one wave per flagged position (unchanged).
__global__ __launch_bounds__(64) void k_repair(const float* __restrict__ x,
                                               const float* __restrict__ w1,
                                               const float* __restrict__ b1,
                                               const float* __restrict__ w2,
                                               const float* __restrict__ b2,
                                               const float* __restrict__ cb,
                                               float* __restrict__ q,
                                               float* __restrict__ idx_out,
                                               const int* __restrict__ nflag,
                                               const int* __restrict__ flags) {
    __shared__ double h1w[16][16];
    __shared__ double xvd[32];
    int lane = threadIdx.x;
    int cnt = *nflag;
    if (cnt > MAXFLAG) cnt = MAXFLAG;

    for (int fi = blockIdx.x; fi < cnt; fi += gridDim.x) {
        int pos = flags[fi];
        int n = pos >> 12, sp = pos & 4095, yo = sp >> 6, xo = sp & 63;

        int pix = lane >> 2, cg = lane & 3;
        int dy = pix >> 2, dx = pix & 3;
        int yh = 2 * yo - 1 + dy, xh = 2 * xo - 1 + dx;
        double hv[4] = {0.0, 0.0, 0.0, 0.0};
        if (yh >= 0 && yh < 128 && xh >= 0 && xh < 128) {
            const float* xin = x + (size_t)n * 65536;
            double patch[4][4];
            int y0 = 2 * yh - 1, x0 = 2 * xh - 1;
#pragma unroll
            for (int i = 0; i < 4; i++) {
                int iy = y0 + i;
                bool oy = (iy >= 0 && iy < 256);
#pragma unroll
                for (int j = 0; j < 4; j++) {
                    int ix = x0 + j;
                    patch[i][j] = (oy && ix >= 0 && ix < 256) ? (double)xin[iy * 256 + ix] : 0.0;
                }
            }
#pragma unroll
            for (int j = 0; j < 4; j++) {
                int c = cg * 4 + j;
                double mm = -INFINITY;
#pragma unroll
                for (int sy = 0; sy < 2; sy++)
#pragma unroll
                    for (int sx = 0; sx < 2; sx++) {
                        double acc = (double)b1[c];
#pragma unroll
                        for (int ky = 0; ky < 3; ky++)
#pragma unroll
                            for (int kx = 0; kx < 3; kx++)
                                acc += (double)w1[c * 9 + ky * 3 + kx] * patch[sy + ky][sx + kx];
                        mm = fmax(mm, acc);
                    }
                hv[j] = 0.5 * mm * (1.0 + erf(mm * 0.70710678118654752440));
            }
        }
        __syncthreads();
#pragma unroll
        for (int j = 0; j < 4; j++) h1w[cg * 4 + j][pix] = hv[j];
        __syncthreads();

        if (lane < 32) {
            double bb = (double)b2[lane];
            double acc[2][2] = {{bb, bb}, {bb, bb}};
            for (int cin = 0; cin < 16; cin++)
#pragma unroll
                for (int ky = 0; ky < 3; ky++)
#pragma unroll
                    for (int kx = 0; kx < 3; kx++) {
                        double wv = (double)w2[((lane * 16 + cin) * 3 + ky) * 3 + kx];
#pragma unroll
                        for (int sy = 0; sy < 2; sy++)
#pragma unroll
                            for (int sx = 0; sx < 2; sx++)
                                acc[sy][sx] += wv * h1w[cin][(sy + ky) * 4 + (sx + kx)];
                    }
            xvd[lane] = fmax(fmax(acc[0][0], acc[0][1]), fmax(acc[1][0], acc[1][1]));
        }
        __syncthreads();

        double x2 = 0.0;
        for (int d = 0; d < 32; d++) x2 += xvd[d] * xvd[d];
        double best = INFINITY;
        int bi = 0;
        for (int j = 0; j < 8; j++) {
            int k = lane * 8 + j;
            const float* cp = cb + k * 32;
            double c2 = 0.0, dot = 0.0;
#pragma unroll
            for (int d = 0; d < 32; d++) {
                double cd = (double)cp[d];
                c2 += cd * cd;
                dot += xvd[d] * cd;
            }
            double dist = x2 - 2.0 * dot + c2;
            if (dist < best) { best = dist; bi = k; }
        }
#pragma unroll
        for (int o = 32; o > 0; o >>= 1) {
            double od = __shfl_down(best, o);
            int oi = __shfl_down(bi, o);
            if (od < best || (od == best && oi < bi)) { best = od; bi = oi; }
        }
        bi = __shfl(bi, 0);

        if (lane == 0) idx_out[(size_t)n * 4096 + sp] = (float)bi;
        if (lane < 32) q[((size_t)(n * 32 + lane) << 12) + sp] = cb[bi * 32 + lane];
    }
}

// prep: parity decoder weights + split-bf16 conv2 weights [cout][tap10][half][cin8].
__global__ __launch_bounds__(256) void k_prep(const float* __restrict__ w2,
                                              const float* __restrict__ w3,
                                              const float* __restrict__ w4,
                                              unsigned short* __restrict__ w2h,
                                              unsigned short* __restrict__ w2l,
                                              float* __restrict__ wc3,
                                              float* __restrict__ wc4) {
    const int masks[2][2] = {{1, 6}, {3, 4}};
    for (int e = threadIdx.x; e < 8192; e += 256) {
        int cout = e & 15, tap = (e >> 4) & 3, cin = (e >> 6) & 31, pp = e >> 11;
        int rm = masks[pp >> 1][tap >> 1], cm = masks[pp & 1][tap & 1];
        float s = 0.0f;
        for (int ky = 0; ky < 3; ky++)
            if ((rm >> ky) & 1)
                for (int kx = 0; kx < 3; kx++)
                    if ((cm >> kx) & 1) s += w3[(cout * 32 + cin) * 9 + ky * 3 + kx];
        wc3[e] = s;
    }
    for (int e = threadIdx.x; e < 1024; e += 256) {
        int tap = e & 3, cin = (e >> 2) & 15, pp = e >> 6;
        int rm = masks[pp >> 1][tap >> 1], cm = masks[pp & 1][tap & 1];
        float s = 0.0f;
        for (int ky = 0; ky < 3; ky++)
            if ((rm >> ky) & 1)
                for (int kx = 0; kx < 3; kx++)
                    if ((cm >> kx) & 1) s += w4[cin * 9 + ky * 3 + kx];
        wc4[e] = s;
    }
    for (int e = threadIdx.x; e < 5120; e += 256) {
        int cout = e / 160;
        int rem = e - cout * 160;
        int tap = rem >> 4;
        int within = rem & 15;   // half*8 + j
        int cin = within;
        float v = 0.0f;
        if (tap < 9) {
            int ky = tap / 3, kx = tap - 3 * (tap / 3);
            v = w2[((cout * 16 + cin) * 3 + ky) * 3 + kx];
        }
        unsigned short hi = f2bf(v);
        unsigned short lo = f2bf(v - bf2f(hi));
        w2h[e] = hi;
        w2l[e] = lo;
    }
}

// up2+conv3(32->16)+gelu, parity-collapsed (unchanged).
__global__ __launch_bounds__(256) void k_conv3n(const float* __restrict__ q,
                                                const float* __restrict__ wc3,
                                                const float* __restrict__ b3,
                                                float* __restrict__ h3) {
    int t = blockIdx.x * 256 + threadIdx.x;
    int b = t & 63, a = (t >> 6) & 63, n = t >> 12;

    float acc[2][2][16];
#pragma unroll
    for (int c = 0; c < 16; c++) {
        float bv = b3[c];
        acc[0][0][c] = bv; acc[0][1][c] = bv; acc[1][0][c] = bv; acc[1][1][c] = bv;
    }

    for (int cin = 0; cin < 32; cin++) {
        const float* qc = q + ((size_t)(n * 32 + cin) << 12);
        float v[3][3];
#pragma unroll
        for (int r = 0; r < 3; r++) {
            int qy = a - 1 + r;
            bool vy = (qy >= 0 && qy < 64);
#pragma unroll
            for (int cc = 0; cc < 3; cc++) {
                int qx = b - 1 + cc;
                v[r][cc] = (vy && qx >= 0 && qx < 64) ? qc[(qy << 6) + qx] : 0.0f;
            }
        }
        const float* wp = wc3 + cin * 64;
#pragma unroll
        for (int py = 0; py < 2; py++)
#pragma unroll
            for (int px = 0; px < 2; px++) {
                const float* wpp = wp + (py * 2 + px) * 2048;
#pragma unroll
                for (int dy = 0; dy < 2; dy++)
#pragma unroll
                    for (int dx = 0; dx < 2; dx++) {
                        float vv = v[py + dy][px + dx];
                        const float* wt = wpp + (dy * 2 + dx) * 16;
#pragma unroll
                        for (int c = 0; c < 16; c++)
                            acc[py][px][c] += wt[c] * vv;
                    }
            }
    }
#pragma unroll
    for (int c = 0; c < 16; c++)
#pragma unroll
        for (int py = 0; py < 2; py++) {
            float2 f2 = make_float2(GELUF(acc[py][0][c]), GELUF(acc[py][1][c]));
            *(float2*)(h3 + ((size_t)(n * 16 + c) << 14) + ((2 * a + py) << 7) + 2 * b) = f2;
        }
}

// up2+conv4(16->1)+clip, parity-collapsed (unchanged).
__global__ __launch_bounds__(256) void k_conv4n(const float* __restrict__ h3,
                                                const float* __restrict__ wc4,
                                                const float* __restrict__ b4,
                                                float* __restrict__ out) {
    int t = blockIdx.x * 256 + threadIdx.x;
    int b = t & 127, a = (t >> 7) & 127, n = t >> 14;

    float bv = b4[0];
    float acc[2][2] = {{bv, bv}, {bv, bv}};

    for (int cin = 0; cin < 16; cin++) {
        const float* hc = h3 + ((size_t)(n * 16 + cin) << 14);
        float v[3][3];
#pragma unroll
        for (int r = 0; r < 3; r++) {
            int hy = a - 1 + r;
            bool vy = (hy >= 0 && hy < 128);
#pragma unroll
            for (int cc = 0; cc < 3; cc++) {
                int hx = b - 1 + cc;
                v[r][cc] = (vy && hx >= 0 && hx < 128) ? hc[(hy << 7) + hx] : 0.0f;
            }
        }
#pragma unroll
        for (int py = 0; py < 2; py++)
#pragma unroll
            for (int px = 0; px < 2; px++)
#pragma unroll
                for (int dy = 0; dy < 2; dy++)
#pragma unroll
                    for (int dx = 0; dx < 2; dx++)
                        acc[py][px] += wc4[(py * 2 + px) * 64 + cin * 4 + dy * 2 + dx] *
                                       v[py + dy][px + dx];
    }
#pragma unroll
    for (int py = 0; py < 2; py++) {
        float2 f2 = make_float2(fminf(fmaxf(acc[py][0], -1.0f), 1.0f),
                                fminf(fmaxf(acc[py][1], -1.0f), 1.0f));
        *(float2*)(out + (size_t)n * 65536 + (2 * a + py) * 256 + 2 * b) = f2;
    }
}

extern "C" void kernel_launch(void* const* d_in, const int* in_sizes, int n_in,
                              void* d_out, int out_size, void* d_ws, size_t ws_size,
                              hipStream_t stream) {
    const float* x  = (const float*)d_in[0];
    const float* w1 = (const float*)d_in[1];
    const float* b1 = (const float*)d_in[2];
    const float* w2 = (const float*)d_in[3];
    const float* b2 = (const float*)d_in[4];
    const float* cb = (const float*)d_in[5];
    const float* w3 = (const float*)d_in[6];
    const float* b3 = (const float*)d_in[7];
    const float* w4 = (const float*)d_in[8];
    const float* b4 = (const float*)d_in[9];

    float* out      = (float*)d_out;
    float* idx_out  = out + 4194304;
    float* loss_out = out + 4194304 + 262144;

    char* ws = (char*)d_ws;
    unsigned short* h1h = (unsigned short*)ws;                      // [0,32M)
    unsigned short* h1l = (unsigned short*)(ws + (size_t)33554432); // [32M,64M)
    float* h2  = (float*)(ws + (size_t)67108864);                   // [64M,96M)
    float* h3  = (float*)ws;                                        // [0,64M) after conv2
    size_t T = 100663296;
    float* wc3 = (float*)(ws + T);                    // 32 KB
    float* wc4 = (float*)(ws + T + 32768);            // 4 KB
    unsigned short* w2h = (unsigned short*)(ws + T + 36864);   // 10240 B
    unsigned short* w2l = (unsigned short*)(ws + T + 47104);   // 10240 B
    int* nflag = (int*)(ws + T + 57344);
    int* flags = (int*)(ws + T + 57408);              // 256 KB

    (void)hipMemsetAsync(loss_out, 0, 4, stream);
    (void)hipMemsetAsync(nflag, 0, 4, stream);

    k_prep<<<1, 256, 0, stream>>>(w2, w3, w4, w2h, w2l, wc3, wc4);
    k_conv1b<<<4096, 256, 0, stream>>>(x, w1, b1, h1h, h1l);
    k_conv2m<<<4096, 256, 0, stream>>>(h1h, h1l, w2h, w2l, b2, h2);
    k_vq_mfma<<<1024, 256, 0, stream>>>(h2, cb, h2, idx_out, loss_out, nflag, flags);
    k_repair<<<4096, 64, 0, stream>>>(x, w1, b1, w2, b2, cb, h2, idx_out, nflag, flags);
    k_conv3n<<<1024, 256, 0, stream>>>(h2, wc3, b3, h3);
    k_conv4n<<<4096, 256, 0, stream>>>(h3, wc4, b4, out);
}

// Round 8
// 477.430 us; speedup vs baseline: 3.7005x; 1.2436x over previous
//
#include <hip/hip_runtime.h>
#include <math.h>

// ---------------------------------------------------------------------------
// SimpleVQAutoEncoder forward.
// conv1 -> h1 as split-bf16 hi/lo, layout [n][y][x][cin] (coalesced).
// conv2: split-bf16 MFMA GEMM over (tap,cin) K=144 (5 K-steps of 32),
//   in-register maxpool from MFMA C-layout, bias post-max.
// VQ: split-bf16 MFMA distances + near-tie flagging; fp64 repair pass
//   recomputes full encoder chain for flagged positions (indices == numpy).
//   eps = 0.02+0.0005|best| (~10x worst-case split-bf16 error ~2e-3);
//   MAXFLAG=262144 (no overflow possible), repair grid 16384 (1-2 pos/wave).
// Decoder: parity-collapsed 2x2 convs.
// Outputs d_out (fp32): recon 4194304 | indices 262144 | loss 1
// ---------------------------------------------------------------------------

#define GELUF(v) (0.5f * (v) * (1.0f + erff((v) * 0.70710678118654752440f)))
#define MAXFLAG 262144

typedef __attribute__((ext_vector_type(8))) short short8;
typedef __attribute__((ext_vector_type(4))) short short4v;
typedef __attribute__((ext_vector_type(4))) float float4v;

static __device__ inline unsigned short f2bf(float f) {
    unsigned u = __float_as_uint(f);
    unsigned r = (u + 0x7FFFu + ((u >> 16) & 1u)) >> 16;
    return (unsigned short)r;
}
static __device__ inline float bf2f(unsigned short h) {
    return __uint_as_float(((unsigned)h) << 16);
}

// conv1 (1->16) + maxpool2 + gelu; output split-bf16 hi/lo [n][y][x][cin].
__global__ __launch_bounds__(256) void k_conv1b(const float* __restrict__ x,
                                                const float* __restrict__ w1,
                                                const float* __restrict__ b1,
                                                unsigned short* __restrict__ h1h,
                                                unsigned short* __restrict__ h1l) {
    int idx = blockIdx.x * 256 + threadIdx.x;
    int xo = idx & 127;
    int yo = (idx >> 7) & 127;
    int n  = idx >> 14;
    const float* xin = x + (size_t)n * 65536;

    float patch[4][4];
    int y0 = 2 * yo - 1, x0 = 2 * xo - 1;
#pragma unroll
    for (int i = 0; i < 4; i++) {
        int iy = y0 + i;
        bool oy = (iy >= 0 && iy < 256);
#pragma unroll
        for (int j = 0; j < 4; j++) {
            int ix = x0 + j;
            patch[i][j] = (oy && ix >= 0 && ix < 256) ? xin[iy * 256 + ix] : 0.0f;
        }
    }
    unsigned short hi[16], lo[16];
#pragma unroll
    for (int c = 0; c < 16; c++) {
        float m = -INFINITY;
#pragma unroll
        for (int sy = 0; sy < 2; sy++)
#pragma unroll
            for (int sx = 0; sx < 2; sx++) {
                float acc = b1[c];
#pragma unroll
                for (int ky = 0; ky < 3; ky++)
#pragma unroll
                    for (int kx = 0; kx < 3; kx++)
                        acc += w1[c * 9 + ky * 3 + kx] * patch[sy + ky][sx + kx];
                m = fmaxf(m, acc);
            }
        float g = GELUF(m);
        hi[c] = f2bf(g);
        lo[c] = f2bf(g - bf2f(hi[c]));
    }
    size_t off = ((size_t)idx) << 4;  // *16 shorts
    uint ph[8], pl[8];
#pragma unroll
    for (int c2 = 0; c2 < 8; c2++) {
        ph[c2] = (uint)hi[2 * c2] | ((uint)hi[2 * c2 + 1] << 16);
        pl[c2] = (uint)lo[2 * c2] | ((uint)lo[2 * c2 + 1] << 16);
    }
    uint4* dh = (uint4*)(h1h + off);
    uint4* dl = (uint4*)(h1l + off);
    dh[0] = make_uint4(ph[0], ph[1], ph[2], ph[3]);
    dh[1] = make_uint4(ph[4], ph[5], ph[6], ph[7]);
    dl[0] = make_uint4(pl[0], pl[1], pl[2], pl[3]);
    dl[1] = make_uint4(pl[4], pl[5], pl[6], pl[7]);
}

// conv2 (16->32) + maxpool2 via split-bf16 MFMA (unchanged from R7).
__global__ __launch_bounds__(256) void k_conv2m(const unsigned short* __restrict__ h1h,
                                                const unsigned short* __restrict__ h1l,
                                                const unsigned short* __restrict__ w2h,
                                                const unsigned short* __restrict__ w2l,
                                                const float* __restrict__ b2,
                                                float* __restrict__ h2) {
    __shared__ unsigned short s_hi[18 * 2 * 18 * 8];
    __shared__ unsigned short s_lo[18 * 2 * 18 * 8];
    __shared__ unsigned short s_wh[32 * 10 * 2 * 8];
    __shared__ unsigned short s_wl[32 * 10 * 2 * 8];
    __shared__ float s_pool[32 * 64];

    int tid = threadIdx.x;
    int n = blockIdx.x >> 6;
    int tile = blockIdx.x & 63;
    int cx0 = (tile & 7) << 4, cy0 = (tile >> 3) << 4;

    {
        const uint* gh = (const uint*)w2h;
        const uint* gl = (const uint*)w2l;
        uint* dh = (uint*)s_wh; uint* dl = (uint*)s_wl;
        for (int e = tid; e < 2560; e += 256) { dh[e] = gh[e]; dl[e] = gl[e]; }
    }
    {
        const uint* gh = (const uint*)(h1h + (((size_t)n) << 18));
        const uint* gl = (const uint*)(h1l + (((size_t)n) << 18));
        uint* dh = (uint*)s_hi; uint* dl = (uint*)s_lo;
        for (int e = tid; e < 2592; e += 256) {
            int r = e / 144;
            int rem = e - r * 144;
            int c = rem >> 3;
            int dw = rem & 7;
            int y = cy0 - 1 + r, xx = cx0 - 1 + c;
            uint vh = 0, vl = 0;
            if (y >= 0 && y < 128 && xx >= 0 && xx < 128) {
                size_t g = ((size_t)((y << 7) + xx) << 3) + dw;
                vh = gh[g]; vl = gl[g];
            }
            int half = dw >> 2;
            int du = (((r * 2 + half) * 18 + c) << 2) + (dw & 3);
            dh[du] = vh; dl[du] = vl;
        }
    }
    __syncthreads();

    int lane = tid & 63, wid = tid >> 6;
    int m = lane & 15, quad = lane >> 4;
    int tl = quad >> 1, half = quad & 1;

    float4v acc[4][2];
#pragma unroll
    for (int mt = 0; mt < 4; mt++)
#pragma unroll
        for (int nt = 0; nt < 2; nt++)
            acc[mt][nt] = (float4v){0.0f, 0.0f, 0.0f, 0.0f};

    for (int s = 0; s < 5; s++) {
        int tA = (s < 4) ? (2 * s + tl) : 8;
        int tB = (s < 4) ? (2 * s + tl) : (8 + tl);
        short8 Bh[2], Bl[2];
#pragma unroll
        for (int nt = 0; nt < 2; nt++) {
            int u = ((nt * 16 + m) * 10 + tB) * 2 + half;
            Bh[nt] = *(const short8*)(s_wh + (u << 3));
            Bl[nt] = *(const short8*)(s_wl + (u << 3));
        }
        int ky = tA / 3, kx = tA - 3 * (tA / 3);
        short8 Ah[4], Al[4];
#pragma unroll
        for (int mt = 0; mt < 4; mt++) {
            int u = (((wid * 4 + mt + ky) * 2 + half) * 18) + m + kx;
            Ah[mt] = *(const short8*)(s_hi + (u << 3));
            Al[mt] = *(const short8*)(s_lo + (u << 3));
        }
#pragma unroll
        for (int mt = 0; mt < 4; mt++)
#pragma unroll
            for (int nt = 0; nt < 2; nt++) {
                float4v z = acc[mt][nt];
                z = __builtin_amdgcn_mfma_f32_16x16x32_bf16(Al[mt], Bh[nt], z, 0, 0, 0);
                z = __builtin_amdgcn_mfma_f32_16x16x32_bf16(Ah[mt], Bl[nt], z, 0, 0, 0);
                z = __builtin_amdgcn_mfma_f32_16x16x32_bf16(Ah[mt], Bh[nt], z, 0, 0, 0);
                acc[mt][nt] = z;
            }
    }

#pragma unroll
    for (int nt = 0; nt < 2; nt++) {
        int cout = nt * 16 + m;
        float bias = b2[cout];
#pragma unroll
        for (int mtp = 0; mtp < 2; mtp++) {
            float4v a0 = acc[2 * mtp][nt], a1 = acc[2 * mtp + 1][nt];
            float p0 = fmaxf(fmaxf(a0[0], a0[1]), fmaxf(a1[0], a1[1])) + bias;
            float p1 = fmaxf(fmaxf(a0[2], a0[3]), fmaxf(a1[2], a1[3])) + bias;
            int py = wid * 2 + mtp;
            int px = quad * 2;
            s_pool[cout * 64 + py * 8 + px]     = p0;
            s_pool[cout * 64 + py * 8 + px + 1] = p1;
        }
    }
    __syncthreads();
    {
        int c = tid >> 3, pr = tid & 7;
        float* dst = h2 + (((size_t)(n * 32 + c)) << 12) + ((cy0 >> 1) + pr) * 64 + (cx0 >> 1);
        const float4* src = (const float4*)(s_pool + c * 64 + pr * 8);
        ((float4*)dst)[0] = src[0];
        ((float4*)dst)[1] = src[1];
    }
}

// VQ via split-bf16 MFMA (eps tightened).
__global__ __launch_bounds__(256) void k_vq_mfma(const float* __restrict__ h2,
                                                 const float* __restrict__ cb,
                                                 float* __restrict__ q,
                                                 float* __restrict__ idx_out,
                                                 float* __restrict__ loss_out,
                                                 int* __restrict__ nflag,
                                                 int* __restrict__ flags) {
    __shared__ unsigned short cbhi[512 * 36];
    __shared__ unsigned short cblo[512 * 36];
    __shared__ float c2s[512];
    __shared__ float s_best[256], s_best2[256];
    __shared__ int   s_bi[256];
    __shared__ float wsum[4];

    int tid = threadIdx.x;

    for (int k = tid; k < 512; k += 256) {
        const float4* row = (const float4*)(cb + k * 32);
        float c2 = 0.0f;
#pragma unroll
        for (int j = 0; j < 8; j++) {
            float4 f4 = row[j];
            float fv[4] = {f4.x, f4.y, f4.z, f4.w};
#pragma unroll
            for (int e = 0; e < 4; e++) {
                float fe = fv[e];
                c2 += fe * fe;
                unsigned short hi = f2bf(fe);
                unsigned short lo = f2bf(fe - bf2f(hi));
                cbhi[k * 36 + j * 4 + e] = hi;
                cblo[k * 36 + j * 4 + e] = lo;
            }
        }
        c2s[k] = c2;
    }
    __syncthreads();

    int lane = tid & 63;
    int wid  = tid >> 6;
    int m    = lane & 15;
    int quad = lane >> 4;

    int img = blockIdx.x >> 4;
    int sp0 = (blockIdx.x & 15) << 8;
    const float* xb = h2 + ((size_t)(img * 32) << 12) + sp0;

    short8 Ahi[4], Alo[4];
    float x2r[4][4];
    float x2own[4];
#pragma unroll
    for (int mt = 0; mt < 4; mt++) {
        const float* xp = xb + wid * 64 + mt * 16 + m;
        float x2 = 0.0f;
#pragma unroll
        for (int j = 0; j < 8; j++) {
            float fe = xp[(size_t)(quad * 8 + j) << 12];
            x2 += fe * fe;
            unsigned short hi = f2bf(fe);
            unsigned short lo = f2bf(fe - bf2f(hi));
            Ahi[mt][j] = (short)hi;
            Alo[mt][j] = (short)lo;
        }
        x2 += __shfl_xor(x2, 16);
        x2 += __shfl_xor(x2, 32);
        x2own[mt] = x2;
    }
#pragma unroll
    for (int mt = 0; mt < 4; mt++)
#pragma unroll
        for (int r = 0; r < 4; r++)
            x2r[mt][r] = __shfl(x2own[mt], quad * 4 + r);

    float best[4][4], best2[4][4];
    int bi[4][4];
#pragma unroll
    for (int mt = 0; mt < 4; mt++)
#pragma unroll
        for (int r = 0; r < 4; r++) {
            best[mt][r] = INFINITY; best2[mt][r] = INFINITY; bi[mt][r] = 0;
        }

    for (int nt = 0; nt < 32; nt++) {
        int ncode = nt * 16 + m;
        short8 Bhi, Blo;
        {
            const short4v* p0 = (const short4v*)&cbhi[ncode * 36 + quad * 8];
            const short4v* p1 = (const short4v*)&cblo[ncode * 36 + quad * 8];
            short4v h0 = p0[0], h1v = p0[1], l0 = p1[0], l1 = p1[1];
#pragma unroll
            for (int e = 0; e < 4; e++) {
                Bhi[e] = h0[e]; Bhi[e + 4] = h1v[e];
                Blo[e] = l0[e]; Blo[e + 4] = l1[e];
            }
        }
        float c2v = c2s[ncode];

        float4v acc[4];
#pragma unroll
        for (int mt = 0; mt < 4; mt++) {
            float4v z = {0.0f, 0.0f, 0.0f, 0.0f};
            z = __builtin_amdgcn_mfma_f32_16x16x32_bf16(Alo[mt], Bhi, z, 0, 0, 0);
            z = __builtin_amdgcn_mfma_f32_16x16x32_bf16(Ahi[mt], Blo, z, 0, 0, 0);
            z = __builtin_amdgcn_mfma_f32_16x16x32_bf16(Ahi[mt], Bhi, z, 0, 0, 0);
            acc[mt] = z;
        }
#pragma unroll
        for (int mt = 0; mt < 4; mt++)
#pragma unroll
            for (int r = 0; r < 4; r++) {
                float dist = fmaf(acc[mt][r], -2.0f, x2r[mt][r] + c2v);
                best2[mt][r] = fminf(best2[mt][r], fmaxf(dist, best[mt][r]));
                bool lt = dist < best[mt][r];
                bi[mt][r] = lt ? ncode : bi[mt][r];
                best[mt][r] = fminf(best[mt][r], dist);
            }
    }

#pragma unroll
    for (int mt = 0; mt < 4; mt++)
#pragma unroll
        for (int r = 0; r < 4; r++) {
            float b1v = best[mt][r], b2v = best2[mt][r];
            int   biv = bi[mt][r];
#pragma unroll
            for (int mask = 1; mask < 16; mask <<= 1) {
                float ob = __shfl_xor(b1v, mask);
                float ob2 = __shfl_xor(b2v, mask);
                int   obi = __shfl_xor(biv, mask);
                b2v = fminf(fminf(b2v, ob2), fmaxf(b1v, ob));
                if (ob < b1v || (ob == b1v && obi < biv)) { b1v = ob; biv = obi; }
            }
            if (m == 0) {
                int p = wid * 64 + mt * 16 + quad * 4 + r;
                s_best[p] = b1v; s_best2[p] = b2v; s_bi[p] = biv;
            }
        }
    __syncthreads();

    int pos = blockIdx.x * 256 + tid;
    float bb = s_best[tid], bb2 = s_best2[tid];
    int   kk = s_bi[tid];
    idx_out[pos] = (float)kk;

    // eps ~10x the worst-case split-bf16 distance error (~2e-3)
    float eps = 0.02f + 0.0005f * fabsf(bb);
    if (bb2 - bb < eps) {
        int slot = atomicAdd(nflag, 1);
        if (slot < MAXFLAG) flags[slot] = pos;
    }

    const float4* crow = (const float4*)(cb + kk * 32);
    float* qp = q + ((size_t)(img * 32) << 12) + sp0 + tid;
#pragma unroll
    for (int j = 0; j < 8; j++) {
        float4 f4 = crow[j];
        qp[(size_t)(j * 4 + 0) << 12] = f4.x;
        qp[(size_t)(j * 4 + 1) << 12] = f4.y;
        qp[(size_t)(j * 4 + 2) << 12] = f4.z;
        qp[(size_t)(j * 4 + 3) << 12] = f4.w;
    }

    float lsum = fmaxf(bb, 0.0f);
#pragma unroll
    for (int o = 32; o > 0; o >>= 1) lsum += __shfl_down(lsum, o);
    if (lane == 0) wsum[wid] = lsum;
    __syncthreads();
    if (tid == 0)
        atomicAdd(loss_out, (wsum[0] + wsum[1] + wsum[2] + wsum[3]) * (1.0f / 8388608.0f));
}

// fp64 repair: one wave per flagged position; grid 16384 (1-2 pos/wave).
__global__ __launch_bounds__(64) void k_repair(const float* __restrict__ x,
                                               const float* __restrict__ w1,
                                               const float* __restrict__ b1,
                                               const float* __restrict__ w2,
                                               const float* __restrict__ b2,
                                               const float* __restrict__ cb,
                                               float* __restrict__ q,
                                               float* __restrict__ idx_out,
                                               const int* __restrict__ nflag,
                                               const int* __restrict__ flags) {
    __shared__ double h1w[16][16];
    __shared__ double xvd[32];
    int lane = threadIdx.x;
    int cnt = *nflag;
    if (cnt > MAXFLAG) cnt = MAXFLAG;

    for (int fi = blockIdx.x; fi < cnt; fi += gridDim.x) {
        int pos = flags[fi];
        int n = pos >> 12, sp = pos & 4095, yo = sp >> 6, xo = sp & 63;

        int pix = lane >> 2, cg = lane & 3;
        int dy = pix >> 2, dx = pix & 3;
        int yh = 2 * yo - 1 + dy, xh = 2 * xo - 1 + dx;
        double hv[4] = {0.0, 0.0, 0.0, 0.0};
        if (yh >= 0 && yh < 128 && xh >= 0 && xh < 128) {
            const float* xin = x + (size_t)n * 65536;
            double patch[4][4];
            int y0 = 2 * yh - 1, x0 = 2 * xh - 1;
#pragma unroll
            for (int i = 0; i < 4; i++) {
                int iy = y0 + i;
                bool oy = (iy >= 0 && iy < 256);
#pragma unroll
                for (int j = 0; j < 4; j++) {
                    int ix = x0 + j;
                    patch[i][j] = (oy && ix >= 0 && ix < 256) ? (double)xin[iy * 256 + ix] : 0.0;
                }
            }
#pragma unroll
            for (int j = 0; j < 4; j++) {
                int c = cg * 4 + j;
                double mm = -INFINITY;
#pragma unroll
                for (int sy = 0; sy < 2; sy++)
#pragma unroll
                    for (int sx = 0; sx < 2; sx++) {
                        double acc = (double)b1[c];
#pragma unroll
                        for (int ky = 0; ky < 3; ky++)
#pragma unroll
                            for (int kx = 0; kx < 3; kx++)
                                acc += (double)w1[c * 9 + ky * 3 + kx] * patch[sy + ky][sx + kx];
                        mm = fmax(mm, acc);
                    }
                hv[j] = 0.5 * mm * (1.0 + erf(mm * 0.70710678118654752440));
            }
        }
        __syncthreads();
#pragma unroll
        for (int j = 0; j < 4; j++) h1w[cg * 4 + j][pix] = hv[j];
        __syncthreads();

        if (lane < 32) {
            double bb = (double)b2[lane];
            double acc[2][2] = {{bb, bb}, {bb, bb}};
            for (int cin = 0; cin < 16; cin++)
#pragma unroll
                for (int ky = 0; ky < 3; ky++)
#pragma unroll
                    for (int kx = 0; kx < 3; kx++) {
                        double wv = (double)w2[((lane * 16 + cin) * 3 + ky) * 3 + kx];
#pragma unroll
                        for (int sy = 0; sy < 2; sy++)
#pragma unroll
                            for (int sx = 0; sx < 2; sx++)
                                acc[sy][sx] += wv * h1w[cin][(sy + ky) * 4 + (sx + kx)];
                    }
            xvd[lane] = fmax(fmax(acc[0][0], acc[0][1]), fmax(acc[1][0], acc[1][1]));
        }
        __syncthreads();

        double x2 = 0.0;
        for (int d = 0; d < 32; d++) x2 += xvd[d] * xvd[d];
        double best = INFINITY;
        int bi = 0;
        for (int j = 0; j < 8; j++) {
            int k = lane * 8 + j;
            const float* cp = cb + k * 32;
            double c2 = 0.0, dot = 0.0;
#pragma unroll
            for (int d = 0; d < 32; d++) {
                double cd = (double)cp[d];
                c2 += cd * cd;
                dot += xvd[d] * cd;
            }
            double dist = x2 - 2.0 * dot + c2;
            if (dist < best) { best = dist; bi = k; }
        }
#pragma unroll
        for (int o = 32; o > 0; o >>= 1) {
            double od = __shfl_down(best, o);
            int oi = __shfl_down(bi, o);
            if (od < best || (od == best && oi < bi)) { best = od; bi = oi; }
        }
        bi = __shfl(bi, 0);

        if (lane == 0) idx_out[(size_t)n * 4096 + sp] = (float)bi;
        if (lane < 32) q[((size_t)(n * 32 + lane) << 12) + sp] = cb[bi * 32 + lane];
    }
}

// prep: parity decoder weights + split-bf16 conv2 weights (unchanged).
__global__ __launch_bounds__(256) void k_prep(const float* __restrict__ w2,
                                              const float* __restrict__ w3,
                                              const float* __restrict__ w4,
                                              unsigned short* __restrict__ w2h,
                                              unsigned short* __restrict__ w2l,
                                              float* __restrict__ wc3,
                                              float* __restrict__ wc4) {
    const int masks[2][2] = {{1, 6}, {3, 4}};
    for (int e = threadIdx.x; e < 8192; e += 256) {
        int cout = e & 15, tap = (e >> 4) & 3, cin = (e >> 6) & 31, pp = e >> 11;
        int rm = masks[pp >> 1][tap >> 1], cm = masks[pp & 1][tap & 1];
        float s = 0.0f;
        for (int ky = 0; ky < 3; ky++)
            if ((rm >> ky) & 1)
                for (int kx = 0; kx < 3; kx++)
                    if ((cm >> kx) & 1) s += w3[(cout * 32 + cin) * 9 + ky * 3 + kx];
        wc3[e] = s;
    }
    for (int e = threadIdx.x; e < 1024; e += 256) {
        int tap = e & 3, cin = (e >> 2) & 15, pp = e >> 6;
        int rm = masks[pp >> 1][tap >> 1], cm = masks[pp & 1][tap & 1];
        float s = 0.0f;
        for (int ky = 0; ky < 3; ky++)
            if ((rm >> ky) & 1)
                for (int kx = 0; kx < 3; kx++)
                    if ((cm >> kx) & 1) s += w4[cin * 9 + ky * 3 + kx];
        wc4[e] = s;
    }
    for (int e = threadIdx.x; e < 5120; e += 256) {
        int cout = e / 160;
        int rem = e - cout * 160;
        int tap = rem >> 4;
        int cin = rem & 15;
        float v = 0.0f;
        if (tap < 9) {
            int ky = tap / 3, kx = tap - 3 * (tap / 3);
            v = w2[((cout * 16 + cin) * 3 + ky) * 3 + kx];
        }
        unsigned short hi = f2bf(v);
        unsigned short lo = f2bf(v - bf2f(hi));
        w2h[e] = hi;
        w2l[e] = lo;
    }
}

// up2+conv3(32->16)+gelu, parity-collapsed (unchanged).
__global__ __launch_bounds__(256) void k_conv3n(const float* __restrict__ q,
                                                const float* __restrict__ wc3,
                                                const float* __restrict__ b3,
                                                float* __restrict__ h3) {
    int t = blockIdx.x * 256 + threadIdx.x;
    int b = t & 63, a = (t >> 6) & 63, n = t >> 12;

    float acc[2][2][16];
#pragma unroll
    for (int c = 0; c < 16; c++) {
        float bv = b3[c];
        acc[0][0][c] = bv; acc[0][1][c] = bv; acc[1][0][c] = bv; acc[1][1][c] = bv;
    }

    for (int cin = 0; cin < 32; cin++) {
        const float* qc = q + ((size_t)(n * 32 + cin) << 12);
        float v[3][3];
#pragma unroll
        for (int r = 0; r < 3; r++) {
            int qy = a - 1 + r;
            bool vy = (qy >= 0 && qy < 64);
#pragma unroll
            for (int cc = 0; cc < 3; cc++) {
                int qx = b - 1 + cc;
                v[r][cc] = (vy && qx >= 0 && qx < 64) ? qc[(qy << 6) + qx] : 0.0f;
            }
        }
        const float* wp = wc3 + cin * 64;
#pragma unroll
        for (int py = 0; py < 2; py++)
#pragma unroll
            for (int px = 0; px < 2; px++) {
                const float* wpp = wp + (py * 2 + px) * 2048;
#pragma unroll
                for (int dy = 0; dy < 2; dy++)
#pragma unroll
                    for (int dx = 0; dx < 2; dx++) {
                        float vv = v[py + dy][px + dx];
                        const float* wt = wpp + (dy * 2 + dx) * 16;
#pragma unroll
                        for (int c = 0; c < 16; c++)
                            acc[py][px][c] += wt[c] * vv;
                    }
            }
    }
#pragma unroll
    for (int c = 0; c < 16; c++)
#pragma unroll
        for (int py = 0; py < 2; py++) {
            float2 f2 = make_float2(GELUF(acc[py][0][c]), GELUF(acc[py][1][c]));
            *(float2*)(h3 + ((size_t)(n * 16 + c) << 14) + ((2 * a + py) << 7) + 2 * b) = f2;
        }
}

// up2+conv4(16->1)+clip, parity-collapsed (unchanged).
__global__ __launch_bounds__(256) void k_conv4n(const float* __restrict__ h3,
                                                const float* __restrict__ wc4,
                                                const float* __restrict__ b4,
                                                float* __restrict__ out) {
    int t = blockIdx.x * 256 + threadIdx.x;
    int b = t & 127, a = (t >> 7) & 127, n = t >> 14;

    float bv = b4[0];
    float acc[2][2] = {{bv, bv}, {bv, bv}};

    for (int cin = 0; cin < 16; cin++) {
        const float* hc = h3 + ((size_t)(n * 16 + cin) << 14);
        float v[3][3];
#pragma unroll
        for (int r = 0; r < 3; r++) {
            int hy = a - 1 + r;
            bool vy = (hy >= 0 && hy < 128);
#pragma unroll
            for (int cc = 0; cc < 3; cc++) {
                int hx = b - 1 + cc;
                v[r][cc] = (vy && hx >= 0 && hx < 128) ? hc[(hy << 7) + hx] : 0.0f;
            }
        }
#pragma unroll
        for (int py = 0; py < 2; py++)
#pragma unroll
            for (int px = 0; px < 2; px++)
#pragma unroll
                for (int dy = 0; dy < 2; dy++)
#pragma unroll
                    for (int dx = 0; dx < 2; dx++)
                        acc[py][px] += wc4[(py * 2 + px) * 64 + cin * 4 + dy * 2 + dx] *
                                       v[py + dy][px + dx];
    }
#pragma unroll
    for (int py = 0; py < 2; py++) {
        float2 f2 = make_float2(fminf(fmaxf(acc[py][0], -1.0f), 1.0f),
                                fminf(fmaxf(acc[py][1], -1.0f), 1.0f));
        *(float2*)(out + (size_t)n * 65536 + (2 * a + py) * 256 + 2 * b) = f2;
    }
}

extern "C" void kernel_launch(void* const* d_in, const int* in_sizes, int n_in,
                              void* d_out, int out_size, void* d_ws, size_t ws_size,
                              hipStream_t stream) {
    const float* x  = (const float*)d_in[0];
    const float* w1 = (const float*)d_in[1];
    const float* b1 = (const float*)d_in[2];
    const float* w2 = (const float*)d_in[3];
    const float* b2 = (const float*)d_in[4];
    const float* cb = (const float*)d_in[5];
    const float* w3 = (const float*)d_in[6];
    const float* b3 = (const float*)d_in[7];
    const float* w4 = (const float*)d_in[8];
    const float* b4 = (const float*)d_in[9];

    float* out      = (float*)d_out;
    float* idx_out  = out + 4194304;
    float* loss_out = out + 4194304 + 262144;

    char* ws = (char*)d_ws;
    unsigned short* h1h = (unsigned short*)ws;                      // [0,32M)
    unsigned short* h1l = (unsigned short*)(ws + (size_t)33554432); // [32M,64M)
    float* h2  = (float*)(ws + (size_t)67108864);                   // [64M,96M)
    float* h3  = (float*)ws;                                        // [0,64M) after conv2
    size_t T = 100663296;
    float* wc3 = (float*)(ws + T);                    // 32 KB
    float* wc4 = (float*)(ws + T + 32768);            // 4 KB
    unsigned short* w2h = (unsigned short*)(ws + T + 36864);   // 10240 B
    unsigned short* w2l = (unsigned short*)(ws + T + 47104);   // 10240 B
    int* nflag = (int*)(ws + T + 57344);
    int* flags = (int*)(ws + T + 57408);              // 1 MB (MAXFLAG=262144)

    (void)hipMemsetAsync(loss_out, 0, 4, stream);
    (void)hipMemsetAsync(nflag, 0, 4, stream);

    k_prep<<<1, 256, 0, stream>>>(w2, w3, w4, w2h, w2l, wc3, wc4);
    k_conv1b<<<4096, 256, 0, stream>>>(x, w1, b1, h1h, h1l);
    k_conv2m<<<4096, 256, 0, stream>>>(h1h, h1l, w2h, w2l, b2, h2);
    k_vq_mfma<<<1024, 256, 0, stream>>>(h2, cb, h2, idx_out, loss_out, nflag, flags);
    k_repair<<<16384, 64, 0, stream>>>(x, w1, b1, w2, b2, cb, h2, idx_out, nflag, flags);
    k_conv3n<<<1024, 256, 0, stream>>>(h2, wc3, b3, h3);
    k_conv4n<<<4096, 256, 0, stream>>>(h3, wc4, b4, out);
}